// Round 1
// baseline (3776.879 us; speedup 1.0000x reference)
//
#include <hip/hip_runtime.h>

#define HID 128
#define NH 8
#define DH 16
#define NLAYERS 7
#define MLP_IN 285

// ---------------- embed: h = node_feats @ W_emb + b_emb ----------------
__global__ __launch_bounds__(256) void embed_kernel(
    const float* __restrict__ nf, const float* __restrict__ We,
    const float* __restrict__ be, float* __restrict__ h, int N)
{
    int idx = blockIdx.x * 256 + threadIdx.x;
    if (idx >= N * HID) return;
    int n = idx >> 7, j = idx & 127;
    h[idx] = fmaf(nf[n * 2], We[j], fmaf(nf[n * 2 + 1], We[HID + j], be[j]));
}

// ---------------- layernorm: one wave per row of 128 ----------------
__global__ __launch_bounds__(256) void ln_kernel(
    const float* __restrict__ h, float* __restrict__ x,
    const float* __restrict__ g, const float* __restrict__ b, int N)
{
    int row = blockIdx.x * 4 + (threadIdx.x >> 6);
    int lane = threadIdx.x & 63;
    if (row >= N) return;
    float a0 = h[row * HID + lane];
    float a1 = h[row * HID + 64 + lane];
    float s = a0 + a1;
#pragma unroll
    for (int off = 32; off > 0; off >>= 1) s += __shfl_down(s, off, 64);
    s = __shfl(s, 0, 64);
    float mu = s * (1.0f / 128.0f);
    float d0 = a0 - mu, d1 = a1 - mu;
    float v = d0 * d0 + d1 * d1;
#pragma unroll
    for (int off = 32; off > 0; off >>= 1) v += __shfl_down(v, off, 64);
    v = __shfl(v, 0, 64);
    float r = rsqrtf(v * (1.0f / 128.0f) + 1e-5f);
    x[row * HID + lane]      = d0 * r * g[lane] + b[lane];
    x[row * HID + 64 + lane] = d1 * r * g[64 + lane] + b[64 + lane];
}

// ---------------- 128x128 GEMM: C[M,128] = A[M,128] @ W[128,128] + bias ----------------
// MODE bit0 = relu, bit1 = residual add (res)
template <int MODE>
__global__ __launch_bounds__(256) void gemm128_kernel(
    const float* __restrict__ A, const float* __restrict__ W,
    const float* __restrict__ bias, const float* __restrict__ res,
    float* __restrict__ C, int M)
{
    __shared__ float As[64][132];
    int tid = threadIdx.x;
    int cg = tid & 15;   // 16 col groups x 4 cols
    int rg = tid >> 4;   // 16 row groups x 4 rows
    int rowBase = blockIdx.x * 64;
    int colBase = blockIdx.y * 64;

    // stage A tile (64 rows x 128 k), float4-coalesced
    for (int i = tid; i < 64 * 32; i += 256) {
        int r = i >> 5;
        int kq = i & 31;
        int row = rowBase + r;
        float4 va = (row < M) ? *(const float4*)&A[(size_t)row * HID + kq * 4]
                              : make_float4(0.f, 0.f, 0.f, 0.f);
        *(float4*)&As[r][kq * 4] = va;
    }
    __syncthreads();

    float acc[4][4];
#pragma unroll
    for (int i = 0; i < 4; ++i)
#pragma unroll
        for (int j = 0; j < 4; ++j) acc[i][j] = 0.f;

    const float* Wc = W + colBase + cg * 4;
    for (int k = 0; k < 128; k += 4) {
        float4 a[4];
#pragma unroll
        for (int i = 0; i < 4; ++i) a[i] = *(const float4*)&As[rg * 4 + i][k];
#pragma unroll
        for (int kk = 0; kk < 4; ++kk) {
            float4 w = *(const float4*)&Wc[(size_t)(k + kk) * HID];
#pragma unroll
            for (int i = 0; i < 4; ++i) {
                float av = ((const float*)&a[i])[kk];
                acc[i][0] = fmaf(av, w.x, acc[i][0]);
                acc[i][1] = fmaf(av, w.y, acc[i][1]);
                acc[i][2] = fmaf(av, w.z, acc[i][2]);
                acc[i][3] = fmaf(av, w.w, acc[i][3]);
            }
        }
    }

    float4 bv = *(const float4*)&bias[colBase + cg * 4];
#pragma unroll
    for (int i = 0; i < 4; ++i) {
        int row = rowBase + rg * 4 + i;
        if (row < M) {
            float4 c;
            c.x = acc[i][0] + bv.x;
            c.y = acc[i][1] + bv.y;
            c.z = acc[i][2] + bv.z;
            c.w = acc[i][3] + bv.w;
            if (MODE & 2) {
                float4 rv = *(const float4*)&res[(size_t)row * HID + colBase + cg * 4];
                c.x += rv.x; c.y += rv.y; c.z += rv.z; c.w += rv.w;
            }
            if (MODE & 1) {
                c.x = fmaxf(c.x, 0.f); c.y = fmaxf(c.y, 0.f);
                c.z = fmaxf(c.z, 0.f); c.w = fmaxf(c.w, 0.f);
            }
            *(float4*)&C[(size_t)row * HID + colBase + cg * 4] = c;
        }
    }
}

// ---------------- attention scores: ex = exp(q.k/4); den += ex ----------------
__global__ __launch_bounds__(256) void scores_kernel(
    const float* __restrict__ q, const float* __restrict__ k,
    const int* __restrict__ src, const int* __restrict__ dst,
    float* __restrict__ ex, float* __restrict__ den, int E)
{
    int idx = blockIdx.x * 256 + threadIdx.x;
    if (idx >= E * NH) return;
    int e = idx >> 3, hh = idx & 7;
    int s = src[e], d = dst[e];
    const float4* qp = (const float4*)&q[(size_t)d * HID + hh * DH];
    const float4* kp = (const float4*)&k[(size_t)s * HID + hh * DH];
    float acc = 0.f;
#pragma unroll
    for (int i = 0; i < 4; ++i) {
        float4 a = qp[i], b = kp[i];
        acc += a.x * b.x + a.y * b.y + a.z * b.z + a.w * b.w;
    }
    float v = __expf(acc * 0.25f);
    ex[idx] = v;
    atomicAdd(&den[d * NH + hh], v);
}

// ---------------- attention accumulate: attnU[dst] += ex * V[src] ----------------
__global__ __launch_bounds__(256) void attnacc_kernel(
    const float* __restrict__ ex, const float* __restrict__ v,
    const int* __restrict__ src, const int* __restrict__ dst,
    float* __restrict__ attnU, int E)
{
    int idx = blockIdx.x * 256 + threadIdx.x;
    if (idx >= E * HID) return;
    int e = idx >> 7, j = idx & 127;
    int hh = j >> 4;
    float w = ex[e * NH + hh];
    atomicAdd(&attnU[(size_t)dst[e] * HID + j], w * v[(size_t)src[e] * HID + j]);
}

// ---------------- normalize: attn = attnU / den (0 if empty segment) ----------------
__global__ __launch_bounds__(256) void attnnorm_kernel(
    float* __restrict__ attnU, const float* __restrict__ den, int N)
{
    int idx = blockIdx.x * 256 + threadIdx.x;
    if (idx >= N * HID) return;
    int n = idx >> 7, j = idx & 127;
    float d = den[n * NH + (j >> 4)];
    attnU[idx] = (d > 0.f) ? attnU[idx] / d : 0.f;
}

// ---------------- fused edge classifier MLP, 32 edges per block ----------------
__global__ __launch_bounds__(256) void edge_mlp_kernel(
    const float* __restrict__ h, const float* __restrict__ ce,
    const float* __restrict__ pe, const float* __restrict__ num,
    const int* __restrict__ src, const int* __restrict__ dst,
    const int* __restrict__ pc, const int* __restrict__ rc,
    const int* __restrict__ pf,
    const float* __restrict__ Wh, const float* __restrict__ bh,
    const float* __restrict__ Wo, const float* __restrict__ bo,
    float* __restrict__ out, int E)
{
    __shared__ float ybuf[32][288];
    int tid = threadIdx.x;
    int e0 = blockIdx.x * 32;

    // stage y0 = [h[src] | h[dst] | ce[pc] | ce[rc] | pe[pf] | num]
    for (int i = tid; i < 32 * MLP_IN; i += 256) {
        int t = i / MLP_IN;
        int k = i - t * MLP_IN;
        int e = e0 + t;
        float v;
        if (k < 128)      v = h[(size_t)src[e] * HID + k];
        else if (k < 256) v = h[(size_t)dst[e] * HID + (k - 128)];
        else if (k < 264) v = ce[pc[e] * 8 + (k - 256)];
        else if (k < 272) v = ce[rc[e] * 8 + (k - 264)];
        else if (k < 280) v = pe[pf[e] * 8 + (k - 272)];
        else              v = num[(size_t)e * 5 + (k - 280)];
        ybuf[t][k] = v;
    }
    __syncthreads();

    int ct = tid & 31;   // col thread: cols ct + 32*i, i<9
    int et = tid >> 5;   // edge thread: edges et*4 .. et*4+3

    for (int layer = 0; layer < 3; ++layer) {
        const float* __restrict__ W = Wh + (size_t)layer * MLP_IN * MLP_IN;
        const float* __restrict__ b = bh + layer * MLP_IN;
        int jidx[9];
        float bv[9];
#pragma unroll
        for (int i = 0; i < 9; ++i) {
            int j = ct + 32 * i;
            jidx[i] = (j < MLP_IN) ? j : 0;
            bv[i] = (j < MLP_IN) ? b[j] : 0.f;
        }
        float acc[9][4];
#pragma unroll
        for (int i = 0; i < 9; ++i)
#pragma unroll
            for (int t = 0; t < 4; ++t) acc[i][t] = 0.f;

        for (int k = 0; k < MLP_IN; ++k) {
            float y0 = ybuf[et * 4 + 0][k];
            float y1 = ybuf[et * 4 + 1][k];
            float y2 = ybuf[et * 4 + 2][k];
            float y3 = ybuf[et * 4 + 3][k];
            const float* wr = W + (size_t)k * MLP_IN;
#pragma unroll
            for (int i = 0; i < 9; ++i) {
                float w = wr[jidx[i]];
                acc[i][0] = fmaf(y0, w, acc[i][0]);
                acc[i][1] = fmaf(y1, w, acc[i][1]);
                acc[i][2] = fmaf(y2, w, acc[i][2]);
                acc[i][3] = fmaf(y3, w, acc[i][3]);
            }
        }
        __syncthreads();  // all reads of ybuf complete
#pragma unroll
        for (int i = 0; i < 9; ++i) {
            int j = ct + 32 * i;
            if (j < MLP_IN) {
#pragma unroll
                for (int t = 0; t < 4; ++t)
                    ybuf[et * 4 + t][j] = fmaxf(acc[i][t] + bv[i], 0.f);
            }
        }
        __syncthreads();  // writes complete before next layer reads
    }

    // output layer: 2 cols
    if (tid < 64) {
        int t = tid >> 1, oc = tid & 1;
        float acc = bo[oc];
        for (int k = 0; k < MLP_IN; ++k)
            acc = fmaf(ybuf[t][k], Wo[k * 2 + oc], acc);
        out[(size_t)(e0 + t) * 2 + oc] = acc;
    }
}

extern "C" void kernel_launch(void* const* d_in, const int* in_sizes, int n_in,
                              void* d_out, int out_size, void* d_ws, size_t ws_size,
                              hipStream_t stream)
{
    const float* node_feats = (const float*)d_in[0];
    const float* numericals = (const float*)d_in[1];
    const float* W_emb = (const float*)d_in[2];
    const float* b_emb = (const float*)d_in[3];
    const float* WQ = (const float*)d_in[4];
    const float* bQ = (const float*)d_in[5];
    const float* WK = (const float*)d_in[6];
    const float* bK = (const float*)d_in[7];
    const float* WV = (const float*)d_in[8];
    const float* bV = (const float*)d_in[9];
    const float* WO = (const float*)d_in[10];
    const float* bO = (const float*)d_in[11];
    const float* ln1_g = (const float*)d_in[12];
    const float* ln1_b = (const float*)d_in[13];
    const float* ln2_g = (const float*)d_in[14];
    const float* ln2_b = (const float*)d_in[15];
    const float* W1 = (const float*)d_in[16];
    const float* b1 = (const float*)d_in[17];
    const float* W2 = (const float*)d_in[18];
    const float* b2 = (const float*)d_in[19];
    const float* curr_emb = (const float*)d_in[20];
    const float* pay_emb = (const float*)d_in[21];
    const float* mlp_Wh = (const float*)d_in[22];
    const float* mlp_bh = (const float*)d_in[23];
    const float* mlp_Wo = (const float*)d_in[24];
    const float* mlp_bo = (const float*)d_in[25];
    const int* src = (const int*)d_in[26];
    const int* dst = (const int*)d_in[27];
    const int* pc = (const int*)d_in[28];
    const int* rc = (const int*)d_in[29];
    const int* pf = (const int*)d_in[30];

    const int N = in_sizes[0] / 2;
    const int E = in_sizes[26];

    float* ws = (float*)d_ws;
    float* h   = ws;
    float* x   = h  + (size_t)N * HID;
    float* qb  = x  + (size_t)N * HID;
    float* kb  = qb + (size_t)N * HID;
    float* vb  = kb + (size_t)N * HID;
    float* at  = vb + (size_t)N * HID;
    float* den = at + (size_t)N * HID;
    float* ex  = den + (size_t)N * NH;

    embed_kernel<<<(N * HID + 255) / 256, 256, 0, stream>>>(node_feats, W_emb, b_emb, h, N);

    dim3 gg((N + 63) / 64, 2);
    int lnBlocks = (N + 3) / 4;

    for (int l = 0; l < NLAYERS; ++l) {
        // zero attnU + den (contiguous)
        hipMemsetAsync(at, 0, ((size_t)N * HID + (size_t)N * NH) * sizeof(float), stream);

        ln_kernel<<<lnBlocks, 256, 0, stream>>>(h, x, ln1_g + l * HID, ln1_b + l * HID, N);
        gemm128_kernel<0><<<gg, 256, 0, stream>>>(x, WQ + (size_t)l * HID * HID, bQ + l * HID, nullptr, qb, N);
        gemm128_kernel<0><<<gg, 256, 0, stream>>>(x, WK + (size_t)l * HID * HID, bK + l * HID, nullptr, kb, N);
        gemm128_kernel<0><<<gg, 256, 0, stream>>>(x, WV + (size_t)l * HID * HID, bV + l * HID, nullptr, vb, N);

        scores_kernel<<<(E * NH + 255) / 256, 256, 0, stream>>>(qb, kb, src, dst, ex, den, E);
        attnacc_kernel<<<(int)(((size_t)E * HID + 255) / 256), 256, 0, stream>>>(ex, vb, src, dst, at, E);
        attnnorm_kernel<<<(N * HID + 255) / 256, 256, 0, stream>>>(at, den, N);

        gemm128_kernel<2><<<gg, 256, 0, stream>>>(at, WO + (size_t)l * HID * HID, bO + l * HID, h, h, N);

        ln_kernel<<<lnBlocks, 256, 0, stream>>>(h, x, ln2_g + l * HID, ln2_b + l * HID, N);
        gemm128_kernel<1><<<gg, 256, 0, stream>>>(x, W1 + (size_t)l * HID * HID, b1 + l * HID, nullptr, qb, N);
        gemm128_kernel<2><<<gg, 256, 0, stream>>>(qb, W2 + (size_t)l * HID * HID, b2 + l * HID, h, h, N);
    }

    edge_mlp_kernel<<<(E + 31) / 32, 256, 0, stream>>>(
        h, curr_emb, pay_emb, numericals, src, dst, pc, rc, pf,
        mlp_Wh, mlp_bh, mlp_Wo, mlp_bo, (float*)d_out, E);
}

// Round 2
// 2302.923 us; speedup vs baseline: 1.6400x; 1.6400x over previous
//
#include <hip/hip_runtime.h>

#define HID 128
#define NH 8
#define DH 16
#define NLAYERS 7
#define MLP_IN 285
#define MP 288          // padded MLP dim (18 x 16)
#define LDW 296         // LDS row stride in bf16 elems (16B-aligned rows, bank-spread)

typedef short short8 __attribute__((ext_vector_type(8)));
typedef float f32x4 __attribute__((ext_vector_type(4)));
typedef unsigned short ushort8 __attribute__((ext_vector_type(8)));

__device__ inline unsigned short f2bf(float f) {
    union { float f; unsigned int u; } v; v.f = f;
    unsigned int r = v.u + 0x7FFF + ((v.u >> 16) & 1);
    return (unsigned short)(r >> 16);
}
__device__ inline float bf2f(unsigned short u) {
    union { unsigned int u; float f; } v; v.u = ((unsigned int)u) << 16;
    return v.f;
}

// ---------------- embed: h = node_feats @ W_emb + b_emb ----------------
__global__ __launch_bounds__(256) void embed_kernel(
    const float* __restrict__ nf, const float* __restrict__ We,
    const float* __restrict__ be, float* __restrict__ h, int N)
{
    int idx = blockIdx.x * 256 + threadIdx.x;
    if (idx >= N * HID) return;
    int n = idx >> 7, j = idx & 127;
    h[idx] = fmaf(nf[n * 2], We[j], fmaf(nf[n * 2 + 1], We[HID + j], be[j]));
}

// ---------------- layernorm: one wave per row of 128 ----------------
__global__ __launch_bounds__(256) void ln_kernel(
    const float* __restrict__ h, float* __restrict__ x,
    const float* __restrict__ g, const float* __restrict__ b, int N)
{
    int row = blockIdx.x * 4 + (threadIdx.x >> 6);
    int lane = threadIdx.x & 63;
    if (row >= N) return;
    float a0 = h[row * HID + lane];
    float a1 = h[row * HID + 64 + lane];
    float s = a0 + a1;
#pragma unroll
    for (int off = 32; off > 0; off >>= 1) s += __shfl_down(s, off, 64);
    s = __shfl(s, 0, 64);
    float mu = s * (1.0f / 128.0f);
    float d0 = a0 - mu, d1 = a1 - mu;
    float v = d0 * d0 + d1 * d1;
#pragma unroll
    for (int off = 32; off > 0; off >>= 1) v += __shfl_down(v, off, 64);
    v = __shfl(v, 0, 64);
    float r = rsqrtf(v * (1.0f / 128.0f) + 1e-5f);
    x[row * HID + lane]      = d0 * r * g[lane] + b[lane];
    x[row * HID + 64 + lane] = d1 * r * g[64 + lane] + b[64 + lane];
}

// ---------------- 128x128 GEMM: C[M,128] = A[M,128] @ W[128,128] + bias ----------------
// MODE bit0 = relu, bit1 = residual add (res)
template <int MODE>
__global__ __launch_bounds__(256) void gemm128_kernel(
    const float* __restrict__ A, const float* __restrict__ W,
    const float* __restrict__ bias, const float* __restrict__ res,
    float* __restrict__ C, int M)
{
    __shared__ float As[64][132];
    int tid = threadIdx.x;
    int cg = tid & 15;
    int rg = tid >> 4;
    int rowBase = blockIdx.x * 64;
    int colBase = blockIdx.y * 64;

    for (int i = tid; i < 64 * 32; i += 256) {
        int r = i >> 5;
        int kq = i & 31;
        int row = rowBase + r;
        float4 va = (row < M) ? *(const float4*)&A[(size_t)row * HID + kq * 4]
                              : make_float4(0.f, 0.f, 0.f, 0.f);
        *(float4*)&As[r][kq * 4] = va;
    }
    __syncthreads();

    float acc[4][4];
#pragma unroll
    for (int i = 0; i < 4; ++i)
#pragma unroll
        for (int j = 0; j < 4; ++j) acc[i][j] = 0.f;

    const float* Wc = W + colBase + cg * 4;
    for (int k = 0; k < 128; k += 4) {
        float4 a[4];
#pragma unroll
        for (int i = 0; i < 4; ++i) a[i] = *(const float4*)&As[rg * 4 + i][k];
#pragma unroll
        for (int kk = 0; kk < 4; ++kk) {
            float4 w = *(const float4*)&Wc[(size_t)(k + kk) * HID];
#pragma unroll
            for (int i = 0; i < 4; ++i) {
                float av = ((const float*)&a[i])[kk];
                acc[i][0] = fmaf(av, w.x, acc[i][0]);
                acc[i][1] = fmaf(av, w.y, acc[i][1]);
                acc[i][2] = fmaf(av, w.z, acc[i][2]);
                acc[i][3] = fmaf(av, w.w, acc[i][3]);
            }
        }
    }

    float4 bv = *(const float4*)&bias[colBase + cg * 4];
#pragma unroll
    for (int i = 0; i < 4; ++i) {
        int row = rowBase + rg * 4 + i;
        if (row < M) {
            float4 c;
            c.x = acc[i][0] + bv.x;
            c.y = acc[i][1] + bv.y;
            c.z = acc[i][2] + bv.z;
            c.w = acc[i][3] + bv.w;
            if (MODE & 2) {
                float4 rv = *(const float4*)&res[(size_t)row * HID + colBase + cg * 4];
                c.x += rv.x; c.y += rv.y; c.z += rv.z; c.w += rv.w;
            }
            if (MODE & 1) {
                c.x = fmaxf(c.x, 0.f); c.y = fmaxf(c.y, 0.f);
                c.z = fmaxf(c.z, 0.f); c.w = fmaxf(c.w, 0.f);
            }
            *(float4*)&C[(size_t)row * HID + colBase + cg * 4] = c;
        }
    }
}

// ---------------- attention scores ----------------
__global__ __launch_bounds__(256) void scores_kernel(
    const float* __restrict__ q, const float* __restrict__ k,
    const int* __restrict__ src, const int* __restrict__ dst,
    float* __restrict__ ex, float* __restrict__ den, int E)
{
    int idx = blockIdx.x * 256 + threadIdx.x;
    if (idx >= E * NH) return;
    int e = idx >> 3, hh = idx & 7;
    int s = src[e], d = dst[e];
    const float4* qp = (const float4*)&q[(size_t)d * HID + hh * DH];
    const float4* kp = (const float4*)&k[(size_t)s * HID + hh * DH];
    float acc = 0.f;
#pragma unroll
    for (int i = 0; i < 4; ++i) {
        float4 a = qp[i], b = kp[i];
        acc += a.x * b.x + a.y * b.y + a.z * b.z + a.w * b.w;
    }
    float v = __expf(acc * 0.25f);
    ex[idx] = v;
    atomicAdd(&den[d * NH + hh], v);
}

// ---------------- attention accumulate ----------------
__global__ __launch_bounds__(256) void attnacc_kernel(
    const float* __restrict__ ex, const float* __restrict__ v,
    const int* __restrict__ src, const int* __restrict__ dst,
    float* __restrict__ attnU, int E)
{
    int idx = blockIdx.x * 256 + threadIdx.x;
    if (idx >= E * HID) return;
    int e = idx >> 7, j = idx & 127;
    int hh = j >> 4;
    float w = ex[e * NH + hh];
    atomicAdd(&attnU[(size_t)dst[e] * HID + j], w * v[(size_t)src[e] * HID + j]);
}

// ---------------- normalize ----------------
__global__ __launch_bounds__(256) void attnnorm_kernel(
    float* __restrict__ attnU, const float* __restrict__ den, int N)
{
    int idx = blockIdx.x * 256 + threadIdx.x;
    if (idx >= N * HID) return;
    int n = idx >> 7, j = idx & 127;
    float d = den[n * NH + (j >> 4)];
    attnU[idx] = (d > 0.f) ? attnU[idx] / d : 0.f;
}

// ---------------- prep: transpose+pad+bf16 MLP hidden weights ----------------
// wt[l][n][k] = Wh[l][k][n], shape [3][288][288], zero pad
__global__ __launch_bounds__(256) void prep_wt_kernel(
    const float* __restrict__ Wh, unsigned short* __restrict__ wt)
{
    int idx = blockIdx.x * 256 + threadIdx.x;
    if (idx >= 3 * MP * MP) return;
    int l = idx / (MP * MP);
    int r = idx - l * (MP * MP);
    int n = r / MP, k = r - n * MP;
    float v = (n < MLP_IN && k < MLP_IN)
        ? Wh[(size_t)l * MLP_IN * MLP_IN + (size_t)k * MLP_IN + n] : 0.f;
    wt[idx] = f2bf(v);
}

// ---------------- prep: h (fp32) -> hb (bf16) ----------------
__global__ __launch_bounds__(256) void prep_hb_kernel(
    const float* __restrict__ h, unsigned short* __restrict__ hb, int n)
{
    int idx = blockIdx.x * 256 + threadIdx.x;
    if (idx >= n) return;
    hb[idx] = f2bf(h[idx]);
}

// ---------------- fused edge classifier MLP: MFMA bf16, 128 edges/block ----------------
__global__ __launch_bounds__(256) void edge_mlp_mfma(
    const unsigned short* __restrict__ hb, const float* __restrict__ ce,
    const float* __restrict__ pe, const float* __restrict__ num,
    const int* __restrict__ src, const int* __restrict__ dst,
    const int* __restrict__ pc, const int* __restrict__ rc,
    const int* __restrict__ pf,
    const unsigned short* __restrict__ wt, const float* __restrict__ bh,
    const float* __restrict__ Wo, const float* __restrict__ bo,
    float* __restrict__ out, int E)
{
    __shared__ unsigned short y[128 * LDW];
    int tid = threadIdx.x;
    int e0 = blockIdx.x * 128;

    // ---- stage y0: 128 edges x 288 cols bf16; cols 285..287 zero ----
    // 36 chunks of 8 cols per edge
    for (int i = tid; i < 128 * 36; i += 256) {
        int t = i / 36;
        int c = i - t * 36;
        int e = e0 + t;
        if (e >= E) e = E - 1;  // clamp; padded rows never written out
        ushort8 val;
        if (c < 16) {
            val = *(const ushort8*)&hb[(size_t)src[e] * HID + c * 8];
        } else if (c < 32) {
            val = *(const ushort8*)&hb[(size_t)dst[e] * HID + (c - 16) * 8];
        } else if (c == 32) {
            const float* p = &ce[pc[e] * 8];
#pragma unroll
            for (int j = 0; j < 8; ++j) val[j] = f2bf(p[j]);
        } else if (c == 33) {
            const float* p = &ce[rc[e] * 8];
#pragma unroll
            for (int j = 0; j < 8; ++j) val[j] = f2bf(p[j]);
        } else if (c == 34) {
            const float* p = &pe[pf[e] * 8];
#pragma unroll
            for (int j = 0; j < 8; ++j) val[j] = f2bf(p[j]);
        } else {
            const float* p = &num[(size_t)e * 5];
#pragma unroll
            for (int j = 0; j < 5; ++j) val[j] = f2bf(p[j]);
            val[5] = 0; val[6] = 0; val[7] = 0;
        }
        *(ushort8*)&y[t * LDW + c * 8] = val;
    }
    __syncthreads();

    int wave = tid >> 6;
    int lane = tid & 63;
    int l15 = lane & 15;
    int kA = (lane >> 4) * 8;             // base k within a 32-wide k-tile
    int rowA0 = wave * 32 + l15;          // A rows: wave covers rows [32w, 32w+32)
    int rowA1 = rowA0 + 16;
    int rW0 = wave * 32 + (lane >> 4) * 4;  // C writeback row base

    // ---- 3 hidden layers ----
    for (int layer = 0; layer < 3; ++layer) {
        const unsigned short* __restrict__ W = wt + (size_t)layer * MP * MP;
        const float* __restrict__ bias = bh + layer * MLP_IN;

        // load all A fragments for this wave's 32 rows (K = 288 = 9 tiles)
        short8 afr[2][9];
#pragma unroll
        for (int kt = 0; kt < 9; ++kt) {
            afr[0][kt] = *(const short8*)&y[rowA0 * LDW + kt * 32 + kA];
            afr[1][kt] = *(const short8*)&y[rowA1 * LDW + kt * 32 + kA];
        }
        __syncthreads();   // everyone captured A; y is now writable

        for (int ct = 0; ct < 18; ++ct) {
            f32x4 acc0 = {0.f, 0.f, 0.f, 0.f};
            f32x4 acc1 = {0.f, 0.f, 0.f, 0.f};
            const unsigned short* Wp = W + (size_t)(ct * 16 + l15) * MP + kA;
#pragma unroll
            for (int kt = 0; kt < 9; ++kt) {
                short8 b = *(const short8*)&Wp[kt * 32];
                acc0 = __builtin_amdgcn_mfma_f32_16x16x32_bf16(afr[0][kt], b, acc0, 0, 0, 0);
                acc1 = __builtin_amdgcn_mfma_f32_16x16x32_bf16(afr[1][kt], b, acc1, 0, 0, 0);
            }
            int col = ct * 16 + l15;
            if (col < MLP_IN) {
                float bv = bias[col];
#pragma unroll
                for (int i = 0; i < 4; ++i) {
                    float v0 = fmaxf(acc0[i] + bv, 0.f);
                    float v1 = fmaxf(acc1[i] + bv, 0.f);
                    y[(rW0 + i) * LDW + col]        = f2bf(v0);
                    y[(rW0 + i + 16) * LDW + col]   = f2bf(v1);
                }
            }
        }
        __syncthreads();   // y fully updated for next layer
    }

    // ---- output layer: [288] @ Wo[285,2] + bo ----
    {
        int t = tid >> 1, oc = tid & 1;
        int e = e0 + t;
        if (e < E) {
            float acc = bo[oc];
            const unsigned short* yr = &y[t * LDW];
            for (int k = 0; k < MLP_IN; ++k)
                acc = fmaf(bf2f(yr[k]), Wo[k * 2 + oc], acc);
            out[(size_t)e * 2 + oc] = acc;
        }
    }
}

extern "C" void kernel_launch(void* const* d_in, const int* in_sizes, int n_in,
                              void* d_out, int out_size, void* d_ws, size_t ws_size,
                              hipStream_t stream)
{
    const float* node_feats = (const float*)d_in[0];
    const float* numericals = (const float*)d_in[1];
    const float* W_emb = (const float*)d_in[2];
    const float* b_emb = (const float*)d_in[3];
    const float* WQ = (const float*)d_in[4];
    const float* bQ = (const float*)d_in[5];
    const float* WK = (const float*)d_in[6];
    const float* bK = (const float*)d_in[7];
    const float* WV = (const float*)d_in[8];
    const float* bV = (const float*)d_in[9];
    const float* WO = (const float*)d_in[10];
    const float* bO = (const float*)d_in[11];
    const float* ln1_g = (const float*)d_in[12];
    const float* ln1_b = (const float*)d_in[13];
    const float* ln2_g = (const float*)d_in[14];
    const float* ln2_b = (const float*)d_in[15];
    const float* W1 = (const float*)d_in[16];
    const float* b1 = (const float*)d_in[17];
    const float* W2 = (const float*)d_in[18];
    const float* b2 = (const float*)d_in[19];
    const float* curr_emb = (const float*)d_in[20];
    const float* pay_emb = (const float*)d_in[21];
    const float* mlp_Wh = (const float*)d_in[22];
    const float* mlp_bh = (const float*)d_in[23];
    const float* mlp_Wo = (const float*)d_in[24];
    const float* mlp_bo = (const float*)d_in[25];
    const int* src = (const int*)d_in[26];
    const int* dst = (const int*)d_in[27];
    const int* pc = (const int*)d_in[28];
    const int* rc = (const int*)d_in[29];
    const int* pf = (const int*)d_in[30];

    const int N = in_sizes[0] / 2;
    const int E = in_sizes[26];

    float* ws = (float*)d_ws;
    float* h   = ws;
    float* x   = h  + (size_t)N * HID;
    float* qb  = x  + (size_t)N * HID;
    float* kb  = qb + (size_t)N * HID;
    float* vb  = kb + (size_t)N * HID;
    float* at  = vb + (size_t)N * HID;
    float* den = at + (size_t)N * HID;
    float* ex  = den + (size_t)N * NH;
    unsigned short* hb = (unsigned short*)(ex + (size_t)E * NH);
    unsigned short* wt = hb + (size_t)N * HID;

    // prep transposed bf16 MLP weights (graph-safe, reruns every call)
    prep_wt_kernel<<<(3 * MP * MP + 255) / 256, 256, 0, stream>>>(mlp_Wh, wt);

    embed_kernel<<<(N * HID + 255) / 256, 256, 0, stream>>>(node_feats, W_emb, b_emb, h, N);

    dim3 gg((N + 63) / 64, 2);
    int lnBlocks = (N + 3) / 4;

    for (int l = 0; l < NLAYERS; ++l) {
        hipMemsetAsync(at, 0, ((size_t)N * HID + (size_t)N * NH) * sizeof(float), stream);

        ln_kernel<<<lnBlocks, 256, 0, stream>>>(h, x, ln1_g + l * HID, ln1_b + l * HID, N);
        gemm128_kernel<0><<<gg, 256, 0, stream>>>(x, WQ + (size_t)l * HID * HID, bQ + l * HID, nullptr, qb, N);
        gemm128_kernel<0><<<gg, 256, 0, stream>>>(x, WK + (size_t)l * HID * HID, bK + l * HID, nullptr, kb, N);
        gemm128_kernel<0><<<gg, 256, 0, stream>>>(x, WV + (size_t)l * HID * HID, bV + l * HID, nullptr, vb, N);

        scores_kernel<<<(E * NH + 255) / 256, 256, 0, stream>>>(qb, kb, src, dst, ex, den, E);
        attnacc_kernel<<<(int)(((size_t)E * HID + 255) / 256), 256, 0, stream>>>(ex, vb, src, dst, at, E);
        attnnorm_kernel<<<(N * HID + 255) / 256, 256, 0, stream>>>(at, den, N);

        gemm128_kernel<2><<<gg, 256, 0, stream>>>(at, WO + (size_t)l * HID * HID, bO + l * HID, h, h, N);

        ln_kernel<<<lnBlocks, 256, 0, stream>>>(h, x, ln2_g + l * HID, ln2_b + l * HID, N);
        gemm128_kernel<1><<<gg, 256, 0, stream>>>(x, W1 + (size_t)l * HID * HID, b1 + l * HID, nullptr, qb, N);
        gemm128_kernel<2><<<gg, 256, 0, stream>>>(qb, W2 + (size_t)l * HID * HID, b2 + l * HID, h, h, N);
    }

    // bf16 copy of final h for the edge MLP gather
    prep_hb_kernel<<<(N * HID + 255) / 256, 256, 0, stream>>>(h, hb, N * HID);

    edge_mlp_mfma<<<(E + 127) / 128, 256, 0, stream>>>(
        hb, curr_emb, pay_emb, numericals, src, dst, pc, rc, pf,
        wt, mlp_bh, mlp_Wo, mlp_bo, (float*)d_out, E);
}

// Round 3
// 1765.369 us; speedup vs baseline: 2.1394x; 1.3045x over previous
//
#include <hip/hip_runtime.h>

#define HID 128
#define NH 8
#define DH 16
#define NLAYERS 7
#define MLP_IN 285
#define MP 288          // padded MLP dim (18 x 16)
#define LDW 296         // LDS row stride in bf16 elems (16B-aligned rows)

typedef short short8 __attribute__((ext_vector_type(8)));
typedef float f32x4 __attribute__((ext_vector_type(4)));
typedef float f32x16 __attribute__((ext_vector_type(16)));
typedef unsigned short ushort8 __attribute__((ext_vector_type(8)));

__device__ inline unsigned short f2bf(float f) {
    union { float f; unsigned int u; } v; v.f = f;
    unsigned int r = v.u + 0x7FFF + ((v.u >> 16) & 1);
    return (unsigned short)(r >> 16);
}
__device__ inline float bf2f(unsigned short u) {
    union { unsigned int u; float f; } v; v.u = ((unsigned int)u) << 16;
    return v.f;
}

// ---------------- embed: h = node_feats @ W_emb + b_emb ----------------
__global__ __launch_bounds__(256) void embed_kernel(
    const float* __restrict__ nf, const float* __restrict__ We,
    const float* __restrict__ be, float* __restrict__ h, int N)
{
    int idx = blockIdx.x * 256 + threadIdx.x;
    if (idx >= N * HID) return;
    int n = idx >> 7, j = idx & 127;
    h[idx] = fmaf(nf[n * 2], We[j], fmaf(nf[n * 2 + 1], We[HID + j], be[j]));
}

// ---------------- layernorm: one wave per row of 128 ----------------
__global__ __launch_bounds__(256) void ln_kernel(
    const float* __restrict__ h, float* __restrict__ x,
    const float* __restrict__ g, const float* __restrict__ b, int N)
{
    int row = blockIdx.x * 4 + (threadIdx.x >> 6);
    int lane = threadIdx.x & 63;
    if (row >= N) return;
    float a0 = h[row * HID + lane];
    float a1 = h[row * HID + 64 + lane];
    float s = a0 + a1;
#pragma unroll
    for (int off = 32; off > 0; off >>= 1) s += __shfl_down(s, off, 64);
    s = __shfl(s, 0, 64);
    float mu = s * (1.0f / 128.0f);
    float d0 = a0 - mu, d1 = a1 - mu;
    float v = d0 * d0 + d1 * d1;
#pragma unroll
    for (int off = 32; off > 0; off >>= 1) v += __shfl_down(v, off, 64);
    v = __shfl(v, 0, 64);
    float r = rsqrtf(v * (1.0f / 128.0f) + 1e-5f);
    x[row * HID + lane]      = d0 * r * g[lane] + b[lane];
    x[row * HID + 64 + lane] = d1 * r * g[64 + lane] + b[64 + lane];
}

// ---------------- 128x128 GEMM (fp32 vector) ----------------
// MODE bit0 = relu, bit1 = residual add (res)
template <int MODE>
__global__ __launch_bounds__(256) void gemm128_kernel(
    const float* __restrict__ A, const float* __restrict__ W,
    const float* __restrict__ bias, const float* __restrict__ res,
    float* __restrict__ C, int M)
{
    __shared__ float As[64][132];
    int tid = threadIdx.x;
    int cg = tid & 15;
    int rg = tid >> 4;
    int rowBase = blockIdx.x * 64;
    int colBase = blockIdx.y * 64;

    for (int i = tid; i < 64 * 32; i += 256) {
        int r = i >> 5;
        int kq = i & 31;
        int row = rowBase + r;
        float4 va = (row < M) ? *(const float4*)&A[(size_t)row * HID + kq * 4]
                              : make_float4(0.f, 0.f, 0.f, 0.f);
        *(float4*)&As[r][kq * 4] = va;
    }
    __syncthreads();

    float acc[4][4];
#pragma unroll
    for (int i = 0; i < 4; ++i)
#pragma unroll
        for (int j = 0; j < 4; ++j) acc[i][j] = 0.f;

    const float* Wc = W + colBase + cg * 4;
    for (int k = 0; k < 128; k += 4) {
        float4 a[4];
#pragma unroll
        for (int i = 0; i < 4; ++i) a[i] = *(const float4*)&As[rg * 4 + i][k];
#pragma unroll
        for (int kk = 0; kk < 4; ++kk) {
            float4 w = *(const float4*)&Wc[(size_t)(k + kk) * HID];
#pragma unroll
            for (int i = 0; i < 4; ++i) {
                float av = ((const float*)&a[i])[kk];
                acc[i][0] = fmaf(av, w.x, acc[i][0]);
                acc[i][1] = fmaf(av, w.y, acc[i][1]);
                acc[i][2] = fmaf(av, w.z, acc[i][2]);
                acc[i][3] = fmaf(av, w.w, acc[i][3]);
            }
        }
    }

    float4 bv = *(const float4*)&bias[colBase + cg * 4];
#pragma unroll
    for (int i = 0; i < 4; ++i) {
        int row = rowBase + rg * 4 + i;
        if (row < M) {
            float4 c;
            c.x = acc[i][0] + bv.x;
            c.y = acc[i][1] + bv.y;
            c.z = acc[i][2] + bv.z;
            c.w = acc[i][3] + bv.w;
            if (MODE & 2) {
                float4 rv = *(const float4*)&res[(size_t)row * HID + colBase + cg * 4];
                c.x += rv.x; c.y += rv.y; c.z += rv.z; c.w += rv.w;
            }
            if (MODE & 1) {
                c.x = fmaxf(c.x, 0.f); c.y = fmaxf(c.y, 0.f);
                c.z = fmaxf(c.z, 0.f); c.w = fmaxf(c.w, 0.f);
            }
            *(float4*)&C[(size_t)row * HID + colBase + cg * 4] = c;
        }
    }
}

// ---------------- CSR build ----------------
__global__ __launch_bounds__(256) void deg_kernel(
    const int* __restrict__ dst, int* __restrict__ deg, int E)
{
    int e = blockIdx.x * 256 + threadIdx.x;
    if (e < E) atomicAdd(&deg[dst[e]], 1);
}

// single-block exclusive scan of deg -> rowptr (+cursor copy); rowptr[N]=E
__global__ __launch_bounds__(256) void scan_kernel(
    const int* __restrict__ deg, int* __restrict__ rowptr,
    int* __restrict__ cursor, int N)
{
    __shared__ int sums[256];
    int tid = threadIdx.x;
    int chunk = (N + 255) / 256;
    int lo = tid * chunk;
    int hi = lo + chunk; if (hi > N) hi = N;
    int s = 0;
    for (int i = lo; i < hi && i >= 0; ++i) s += deg[i];
    sums[tid] = s;
    __syncthreads();
    for (int off = 1; off < 256; off <<= 1) {
        int v = (tid >= off) ? sums[tid - off] : 0;
        __syncthreads();
        sums[tid] += v;
        __syncthreads();
    }
    int base = (tid == 0) ? 0 : sums[tid - 1];
    for (int i = lo; i < hi; ++i) {
        rowptr[i] = base; cursor[i] = base; base += deg[i];
    }
    if (tid == 255) rowptr[N] = sums[255];
}

__global__ __launch_bounds__(256) void scatter_kernel(
    const int* __restrict__ src, const int* __restrict__ dst,
    int* __restrict__ cursor, int* __restrict__ ssrc, int E)
{
    int e = blockIdx.x * 256 + threadIdx.x;
    if (e < E) {
        int p = atomicAdd(&cursor[dst[e]], 1);
        ssrc[p] = src[e];
    }
}

// ---------------- fused segment-softmax attention: one wave per dst node ----------------
__global__ __launch_bounds__(256) void attn_fused_kernel(
    const float* __restrict__ q, const float* __restrict__ k,
    const float* __restrict__ v, const int* __restrict__ rowptr,
    const int* __restrict__ ssrc, float* __restrict__ at, int N)
{
    int node = blockIdx.x * 4 + (threadIdx.x >> 6);
    int lane = threadIdx.x & 63;
    if (node >= N) return;
    int beg = rowptr[node], end = rowptr[node + 1];
    float q0 = q[(size_t)node * HID + lane];
    float q1 = q[(size_t)node * HID + 64 + lane];
    float acc0 = 0.f, acc1 = 0.f, den0 = 0.f, den1 = 0.f;
    for (int i = beg; i < end; ++i) {
        int s = ssrc[i];
        float k0 = k[(size_t)s * HID + lane];
        float k1 = k[(size_t)s * HID + 64 + lane];
        float p0 = q0 * k0, p1 = q1 * k1;
#pragma unroll
        for (int off = 1; off < 16; off <<= 1) {
            p0 += __shfl_xor(p0, off, 64);
            p1 += __shfl_xor(p1, off, 64);
        }
        float w0 = __expf(p0 * 0.25f);
        float w1 = __expf(p1 * 0.25f);
        den0 += w0; den1 += w1;
        acc0 = fmaf(w0, v[(size_t)s * HID + lane], acc0);
        acc1 = fmaf(w1, v[(size_t)s * HID + 64 + lane], acc1);
    }
    at[(size_t)node * HID + lane]      = (den0 > 0.f) ? acc0 / den0 : 0.f;
    at[(size_t)node * HID + 64 + lane] = (den1 > 0.f) ? acc1 / den1 : 0.f;
}

// ---------------- prep: transpose+pad+bf16 MLP hidden weights ----------------
__global__ __launch_bounds__(256) void prep_wt_kernel(
    const float* __restrict__ Wh, unsigned short* __restrict__ wt)
{
    int idx = blockIdx.x * 256 + threadIdx.x;
    if (idx >= 3 * MP * MP) return;
    int l = idx / (MP * MP);
    int r = idx - l * (MP * MP);
    int n = r / MP, k = r - n * MP;
    float v = (n < MLP_IN && k < MLP_IN)
        ? Wh[(size_t)l * MLP_IN * MLP_IN + (size_t)k * MLP_IN + n] : 0.f;
    wt[idx] = f2bf(v);
}

// ---------------- prep: h (fp32) -> hb (bf16) ----------------
__global__ __launch_bounds__(256) void prep_hb_kernel(
    const float* __restrict__ h, unsigned short* __restrict__ hb, int n)
{
    int idx = blockIdx.x * 256 + threadIdx.x;
    if (idx >= n) return;
    hb[idx] = f2bf(h[idx]);
}

// ---------------- fused edge classifier MLP: 32x32x16 MFMA, 128 edges/block ----------------
__global__ __launch_bounds__(256, 2) void edge_mlp_mfma(
    const unsigned short* __restrict__ hb, const float* __restrict__ ce,
    const float* __restrict__ pe, const float* __restrict__ num,
    const int* __restrict__ src, const int* __restrict__ dst,
    const int* __restrict__ pc, const int* __restrict__ rc,
    const int* __restrict__ pf,
    const unsigned short* __restrict__ wt, const float* __restrict__ bh,
    const float* __restrict__ Wo, const float* __restrict__ bo,
    float* __restrict__ out, int E)
{
    __shared__ unsigned short y[128 * LDW];
    int tid = threadIdx.x;
    int e0 = blockIdx.x * 128;

    // ---- stage y0: 128 edges x 288 cols bf16; cols 285..287 zero ----
    for (int i = tid; i < 128 * 36; i += 256) {
        int t = i / 36;
        int c = i - t * 36;
        int e = e0 + t;
        if (e >= E) e = E - 1;  // clamp; padded rows never written out
        ushort8 val;
        if (c < 16) {
            val = *(const ushort8*)&hb[(size_t)src[e] * HID + c * 8];
        } else if (c < 32) {
            val = *(const ushort8*)&hb[(size_t)dst[e] * HID + (c - 16) * 8];
        } else if (c == 32) {
            const float* p = &ce[pc[e] * 8];
#pragma unroll
            for (int j = 0; j < 8; ++j) val[j] = f2bf(p[j]);
        } else if (c == 33) {
            const float* p = &ce[rc[e] * 8];
#pragma unroll
            for (int j = 0; j < 8; ++j) val[j] = f2bf(p[j]);
        } else if (c == 34) {
            const float* p = &pe[pf[e] * 8];
#pragma unroll
            for (int j = 0; j < 8; ++j) val[j] = f2bf(p[j]);
        } else {
            const float* p = &num[(size_t)e * 5];
#pragma unroll
            for (int j = 0; j < 5; ++j) val[j] = f2bf(p[j]);
            val[5] = 0; val[6] = 0; val[7] = 0;
        }
        *(ushort8*)&y[t * LDW + c * 8] = val;
    }
    __syncthreads();

    int wave = tid >> 6;
    int lane = tid & 63;
    int l31 = lane & 31;
    int half = lane >> 5;
    int rowA = wave * 32 + l31;

    // ---- 3 hidden layers ----
    for (int layer = 0; layer < 3; ++layer) {
        const unsigned short* __restrict__ W = wt + (size_t)layer * MP * MP;
        const float* __restrict__ bias = bh + layer * MLP_IN;

        // A fragments for this wave's 32 rows: 18 k-tiles of 16
        short8 afr[18];
#pragma unroll
        for (int kt = 0; kt < 18; ++kt)
            afr[kt] = *(const short8*)&y[rowA * LDW + kt * 16 + half * 8];
        __syncthreads();   // everyone captured A; y is now writable

        for (int ct = 0; ct < 9; ++ct) {
            f32x16 acc = {};
            const unsigned short* Wp = W + (size_t)(ct * 32 + l31) * MP + half * 8;
            short8 bfr[18];
#pragma unroll
            for (int kt = 0; kt < 18; ++kt)
                bfr[kt] = *(const short8*)&Wp[kt * 16];
#pragma unroll
            for (int kt = 0; kt < 18; ++kt)
                acc = __builtin_amdgcn_mfma_f32_32x32x16_bf16(afr[kt], bfr[kt], acc, 0, 0, 0);

            int col = ct * 32 + l31;
            if (col < MLP_IN) {
                float bv = bias[col];
#pragma unroll
                for (int r = 0; r < 16; ++r) {
                    int rowm = (r & 3) + 8 * (r >> 2) + 4 * half;
                    float vv = fmaxf(acc[r] + bv, 0.f);
                    y[(wave * 32 + rowm) * LDW + col] = f2bf(vv);
                }
            }
        }
        __syncthreads();   // y fully updated for next layer
    }

    // ---- output layer: [288] @ Wo[285,2] + bo ----
    {
        int t = tid >> 1, oc = tid & 1;
        int e = e0 + t;
        if (e < E) {
            float acc = bo[oc];
            const unsigned short* yr = &y[t * LDW];
            for (int k = 0; k < MLP_IN; ++k)
                acc = fmaf(bf2f(yr[k]), Wo[k * 2 + oc], acc);
            out[(size_t)e * 2 + oc] = acc;
        }
    }
}

extern "C" void kernel_launch(void* const* d_in, const int* in_sizes, int n_in,
                              void* d_out, int out_size, void* d_ws, size_t ws_size,
                              hipStream_t stream)
{
    const float* node_feats = (const float*)d_in[0];
    const float* numericals = (const float*)d_in[1];
    const float* W_emb = (const float*)d_in[2];
    const float* b_emb = (const float*)d_in[3];
    const float* WQ = (const float*)d_in[4];
    const float* bQ = (const float*)d_in[5];
    const float* WK = (const float*)d_in[6];
    const float* bK = (const float*)d_in[7];
    const float* WV = (const float*)d_in[8];
    const float* bV = (const float*)d_in[9];
    const float* WO = (const float*)d_in[10];
    const float* bO = (const float*)d_in[11];
    const float* ln1_g = (const float*)d_in[12];
    const float* ln1_b = (const float*)d_in[13];
    const float* ln2_g = (const float*)d_in[14];
    const float* ln2_b = (const float*)d_in[15];
    const float* W1 = (const float*)d_in[16];
    const float* b1 = (const float*)d_in[17];
    const float* W2 = (const float*)d_in[18];
    const float* b2 = (const float*)d_in[19];
    const float* curr_emb = (const float*)d_in[20];
    const float* pay_emb = (const float*)d_in[21];
    const float* mlp_Wh = (const float*)d_in[22];
    const float* mlp_bh = (const float*)d_in[23];
    const float* mlp_Wo = (const float*)d_in[24];
    const float* mlp_bo = (const float*)d_in[25];
    const int* src = (const int*)d_in[26];
    const int* dst = (const int*)d_in[27];
    const int* pc = (const int*)d_in[28];
    const int* rc = (const int*)d_in[29];
    const int* pf = (const int*)d_in[30];

    const int N = in_sizes[0] / 2;
    const int E = in_sizes[26];

    float* ws = (float*)d_ws;
    float* h   = ws;
    float* x   = h  + (size_t)N * HID;
    float* qb  = x  + (size_t)N * HID;
    float* kb  = qb + (size_t)N * HID;
    float* vb  = kb + (size_t)N * HID;
    float* at  = vb + (size_t)N * HID;
    unsigned short* hb = (unsigned short*)(at + (size_t)N * HID);
    unsigned short* wt = hb + (size_t)N * HID;
    int* rowptr = (int*)(wt + 3 * MP * MP);
    int* deg    = rowptr + (N + 1);
    int* cursor = deg + N;
    int* ssrc   = cursor + N;

    // prep transposed bf16 MLP weights (graph-safe, reruns every call)
    prep_wt_kernel<<<(3 * MP * MP + 255) / 256, 256, 0, stream>>>(mlp_Wh, wt);

    embed_kernel<<<(N * HID + 255) / 256, 256, 0, stream>>>(node_feats, W_emb, b_emb, h, N);

    // CSR build (once; src/dst constant across layers)
    hipMemsetAsync(deg, 0, (size_t)N * sizeof(int), stream);
    deg_kernel<<<(E + 255) / 256, 256, 0, stream>>>(dst, deg, E);
    scan_kernel<<<1, 256, 0, stream>>>(deg, rowptr, cursor, N);
    scatter_kernel<<<(E + 255) / 256, 256, 0, stream>>>(src, dst, cursor, ssrc, E);

    dim3 gg((N + 63) / 64, 2);
    int lnBlocks = (N + 3) / 4;

    for (int l = 0; l < NLAYERS; ++l) {
        ln_kernel<<<lnBlocks, 256, 0, stream>>>(h, x, ln1_g + l * HID, ln1_b + l * HID, N);
        gemm128_kernel<0><<<gg, 256, 0, stream>>>(x, WQ + (size_t)l * HID * HID, bQ + l * HID, nullptr, qb, N);
        gemm128_kernel<0><<<gg, 256, 0, stream>>>(x, WK + (size_t)l * HID * HID, bK + l * HID, nullptr, kb, N);
        gemm128_kernel<0><<<gg, 256, 0, stream>>>(x, WV + (size_t)l * HID * HID, bV + l * HID, nullptr, vb, N);

        attn_fused_kernel<<<(N + 3) / 4, 256, 0, stream>>>(qb, kb, vb, rowptr, ssrc, at, N);

        gemm128_kernel<2><<<gg, 256, 0, stream>>>(at, WO + (size_t)l * HID * HID, bO + l * HID, h, h, N);

        ln_kernel<<<lnBlocks, 256, 0, stream>>>(h, x, ln2_g + l * HID, ln2_b + l * HID, N);
        gemm128_kernel<1><<<gg, 256, 0, stream>>>(x, W1 + (size_t)l * HID * HID, b1 + l * HID, nullptr, qb, N);
        gemm128_kernel<2><<<gg, 256, 0, stream>>>(qb, W2 + (size_t)l * HID * HID, b2 + l * HID, h, h, N);
    }

    // bf16 copy of final h for the edge MLP gather
    prep_hb_kernel<<<(N * HID + 255) / 256, 256, 0, stream>>>(h, hb, N * HID);

    edge_mlp_mfma<<<(E + 127) / 128, 256, 0, stream>>>(
        hb, curr_emb, pay_emb, numericals, src, dst, pc, rc, pf,
        wt, mlp_bh, mlp_Wo, mlp_bo, (float*)d_out, E);
}

// Round 4
// 1745.673 us; speedup vs baseline: 2.1636x; 1.0113x over previous
//
#include <hip/hip_runtime.h>

#define HID 128
#define NH 8
#define DH 16
#define NLAYERS 7
#define MLP_IN 285
#define MP 288          // padded MLP dim (18 x 16)
#define LDW 296         // LDS row stride in bf16 elems (16B-aligned rows)

typedef short short8 __attribute__((ext_vector_type(8)));
typedef float f32x4 __attribute__((ext_vector_type(4)));
typedef float f32x16 __attribute__((ext_vector_type(16)));
typedef unsigned short ushort8 __attribute__((ext_vector_type(8)));

__device__ inline unsigned short f2bf(float f) {
    union { float f; unsigned int u; } v; v.f = f;
    unsigned int r = v.u + 0x7FFF + ((v.u >> 16) & 1);
    return (unsigned short)(r >> 16);
}
__device__ inline float bf2f(unsigned short u) {
    union { unsigned int u; float f; } v; v.u = ((unsigned int)u) << 16;
    return v.f;
}

// ---------------- embed: h = node_feats @ W_emb + b_emb ----------------
__global__ __launch_bounds__(256) void embed_kernel(
    const float* __restrict__ nf, const float* __restrict__ We,
    const float* __restrict__ be, float* __restrict__ h, int N)
{
    int idx = blockIdx.x * 256 + threadIdx.x;
    if (idx >= N * HID) return;
    int n = idx >> 7, j = idx & 127;
    h[idx] = fmaf(nf[n * 2], We[j], fmaf(nf[n * 2 + 1], We[HID + j], be[j]));
}

// ---------------- layernorm: one wave per row of 128 ----------------
__global__ __launch_bounds__(256) void ln_kernel(
    const float* __restrict__ h, float* __restrict__ x,
    const float* __restrict__ g, const float* __restrict__ b, int N)
{
    int row = blockIdx.x * 4 + (threadIdx.x >> 6);
    int lane = threadIdx.x & 63;
    if (row >= N) return;
    float a0 = h[row * HID + lane];
    float a1 = h[row * HID + 64 + lane];
    float s = a0 + a1;
#pragma unroll
    for (int off = 32; off > 0; off >>= 1) s += __shfl_down(s, off, 64);
    s = __shfl(s, 0, 64);
    float mu = s * (1.0f / 128.0f);
    float d0 = a0 - mu, d1 = a1 - mu;
    float v = d0 * d0 + d1 * d1;
#pragma unroll
    for (int off = 32; off > 0; off >>= 1) v += __shfl_down(v, off, 64);
    v = __shfl(v, 0, 64);
    float r = rsqrtf(v * (1.0f / 128.0f) + 1e-5f);
    x[row * HID + lane]      = d0 * r * g[lane] + b[lane];
    x[row * HID + 64 + lane] = d1 * r * g[64 + lane] + b[64 + lane];
}

// ---------------- 128x128 GEMM (fp32 vector), W tile staged in LDS ----------------
// MODE bit0 = relu, bit1 = residual add (res)
template <int MODE>
__global__ __launch_bounds__(256) void gemm128_kernel(
    const float* __restrict__ A, const float* __restrict__ W,
    const float* __restrict__ bias, const float* __restrict__ res,
    float* __restrict__ C, int M)
{
    __shared__ float As[64][132];
    __shared__ float Ws[128][68];
    int tid = threadIdx.x;
    int cg = tid & 15;
    int rg = tid >> 4;
    int rowBase = blockIdx.x * 64;
    int colBase = blockIdx.y * 64;

    // stage A tile (64 rows x 128 k)
    for (int i = tid; i < 64 * 32; i += 256) {
        int r = i >> 5;
        int kq = i & 31;
        int row = rowBase + r;
        float4 va = (row < M) ? *(const float4*)&A[(size_t)row * HID + kq * 4]
                              : make_float4(0.f, 0.f, 0.f, 0.f);
        *(float4*)&As[r][kq * 4] = va;
    }
    // stage W tile (128 k x 64 cols), coalesced
    for (int i = tid; i < 128 * 16; i += 256) {
        int k = i >> 4;
        int c4 = i & 15;
        *(float4*)&Ws[k][c4 * 4] = *(const float4*)&W[(size_t)k * HID + colBase + c4 * 4];
    }
    __syncthreads();

    float acc[4][4];
#pragma unroll
    for (int i = 0; i < 4; ++i)
#pragma unroll
        for (int j = 0; j < 4; ++j) acc[i][j] = 0.f;

    for (int k = 0; k < 128; k += 4) {
        float4 a[4];
#pragma unroll
        for (int i = 0; i < 4; ++i) a[i] = *(const float4*)&As[rg * 4 + i][k];
#pragma unroll
        for (int kk = 0; kk < 4; ++kk) {
            float4 w = *(const float4*)&Ws[k + kk][cg * 4];
#pragma unroll
            for (int i = 0; i < 4; ++i) {
                float av = ((const float*)&a[i])[kk];
                acc[i][0] = fmaf(av, w.x, acc[i][0]);
                acc[i][1] = fmaf(av, w.y, acc[i][1]);
                acc[i][2] = fmaf(av, w.z, acc[i][2]);
                acc[i][3] = fmaf(av, w.w, acc[i][3]);
            }
        }
    }

    float4 bv = *(const float4*)&bias[colBase + cg * 4];
#pragma unroll
    for (int i = 0; i < 4; ++i) {
        int row = rowBase + rg * 4 + i;
        if (row < M) {
            float4 c;
            c.x = acc[i][0] + bv.x;
            c.y = acc[i][1] + bv.y;
            c.z = acc[i][2] + bv.z;
            c.w = acc[i][3] + bv.w;
            if (MODE & 2) {
                float4 rv = *(const float4*)&res[(size_t)row * HID + colBase + cg * 4];
                c.x += rv.x; c.y += rv.y; c.z += rv.z; c.w += rv.w;
            }
            if (MODE & 1) {
                c.x = fmaxf(c.x, 0.f); c.y = fmaxf(c.y, 0.f);
                c.z = fmaxf(c.z, 0.f); c.w = fmaxf(c.w, 0.f);
            }
            *(float4*)&C[(size_t)row * HID + colBase + cg * 4] = c;
        }
    }
}

// ---------------- CSR build ----------------
__global__ __launch_bounds__(256) void deg_kernel(
    const int* __restrict__ dst, int* __restrict__ deg, int E)
{
    int e = blockIdx.x * 256 + threadIdx.x;
    if (e < E) atomicAdd(&deg[dst[e]], 1);
}

__global__ __launch_bounds__(256) void scan_kernel(
    const int* __restrict__ deg, int* __restrict__ rowptr,
    int* __restrict__ cursor, int N)
{
    __shared__ int sums[256];
    int tid = threadIdx.x;
    int chunk = (N + 255) / 256;
    int lo = tid * chunk;
    int hi = lo + chunk; if (hi > N) hi = N;
    int s = 0;
    for (int i = lo; i < hi && i >= 0; ++i) s += deg[i];
    sums[tid] = s;
    __syncthreads();
    for (int off = 1; off < 256; off <<= 1) {
        int v = (tid >= off) ? sums[tid - off] : 0;
        __syncthreads();
        sums[tid] += v;
        __syncthreads();
    }
    int base = (tid == 0) ? 0 : sums[tid - 1];
    for (int i = lo; i < hi; ++i) {
        rowptr[i] = base; cursor[i] = base; base += deg[i];
    }
    if (tid == 255) rowptr[N] = sums[255];
}

__global__ __launch_bounds__(256) void scatter_kernel(
    const int* __restrict__ src, const int* __restrict__ dst,
    int* __restrict__ cursor, int* __restrict__ ssrc, int E)
{
    int e = blockIdx.x * 256 + threadIdx.x;
    if (e < E) {
        int p = atomicAdd(&cursor[dst[e]], 1);
        ssrc[p] = src[e];
    }
}

// ---------------- fused segment-softmax attention: one wave per dst node ----------------
__global__ __launch_bounds__(256) void attn_fused_kernel(
    const float* __restrict__ q, const float* __restrict__ k,
    const float* __restrict__ v, const int* __restrict__ rowptr,
    const int* __restrict__ ssrc, float* __restrict__ at, int N)
{
    int node = blockIdx.x * 4 + (threadIdx.x >> 6);
    int lane = threadIdx.x & 63;
    if (node >= N) return;
    int beg = rowptr[node], end = rowptr[node + 1];
    float q0 = q[(size_t)node * HID + lane];
    float q1 = q[(size_t)node * HID + 64 + lane];
    float acc0 = 0.f, acc1 = 0.f, den0 = 0.f, den1 = 0.f;
    for (int i = beg; i < end; ++i) {
        int s = ssrc[i];
        float k0 = k[(size_t)s * HID + lane];
        float k1 = k[(size_t)s * HID + 64 + lane];
        float p0 = q0 * k0, p1 = q1 * k1;
#pragma unroll
        for (int off = 1; off < 16; off <<= 1) {
            p0 += __shfl_xor(p0, off, 64);
            p1 += __shfl_xor(p1, off, 64);
        }
        float w0 = __expf(p0 * 0.25f);
        float w1 = __expf(p1 * 0.25f);
        den0 += w0; den1 += w1;
        acc0 = fmaf(w0, v[(size_t)s * HID + lane], acc0);
        acc1 = fmaf(w1, v[(size_t)s * HID + 64 + lane], acc1);
    }
    at[(size_t)node * HID + lane]      = (den0 > 0.f) ? acc0 / den0 : 0.f;
    at[(size_t)node * HID + 64 + lane] = (den1 > 0.f) ? acc1 / den1 : 0.f;
}

// ---------------- prep: fragment-major packed bf16 MLP hidden weights ----------------
// wp chunk index: ((layer*9 + ct)*18 + kt)*64 + lane ; 8 bf16 per chunk.
// element j: B[k][n] with n = ct*32 + (lane&31), k = kt*16 + (lane>>5)*8 + j
__global__ __launch_bounds__(256) void prep_wp_kernel(
    const float* __restrict__ Wh, unsigned short* __restrict__ wp)
{
    int idx = blockIdx.x * 256 + threadIdx.x;
    if (idx >= 3 * 9 * 18 * 64) return;
    int lane = idx & 63;
    int r = idx >> 6;
    int kt = r % 18; r /= 18;
    int ct = r % 9;
    int layer = r / 9;
    int n = ct * 32 + (lane & 31);
    int kbase = kt * 16 + (lane >> 5) * 8;
    ushort8 val;
#pragma unroll
    for (int j = 0; j < 8; ++j) {
        int k = kbase + j;
        float v = (n < MLP_IN && k < MLP_IN)
            ? Wh[(size_t)layer * MLP_IN * MLP_IN + (size_t)k * MLP_IN + n] : 0.f;
        val[j] = f2bf(v);
    }
    *(ushort8*)&wp[(size_t)idx * 8] = val;
}

// ---------------- prep: h (fp32) -> hb (bf16) ----------------
__global__ __launch_bounds__(256) void prep_hb_kernel(
    const float* __restrict__ h, unsigned short* __restrict__ hb, int n)
{
    int idx = blockIdx.x * 256 + threadIdx.x;
    if (idx >= n) return;
    hb[idx] = f2bf(h[idx]);
}

// ---------------- fused edge classifier MLP: 32x32x16 MFMA, 128 edges/block ----------------
__global__ __launch_bounds__(256, 2) void edge_mlp_mfma(
    const unsigned short* __restrict__ hb, const float* __restrict__ ce,
    const float* __restrict__ pe, const float* __restrict__ num,
    const int* __restrict__ src, const int* __restrict__ dst,
    const int* __restrict__ pc, const int* __restrict__ rc,
    const int* __restrict__ pf,
    const unsigned short* __restrict__ wp, const float* __restrict__ bh,
    const float* __restrict__ Wo, const float* __restrict__ bo,
    float* __restrict__ out, int E)
{
    __shared__ unsigned short y[128 * LDW];
    int tid = threadIdx.x;
    int e0 = blockIdx.x * 128;

    // ---- stage y0: 128 edges x 288 cols bf16; cols 285..287 zero ----
    for (int i = tid; i < 128 * 36; i += 256) {
        int t = i / 36;
        int c = i - t * 36;
        int e = e0 + t;
        if (e >= E) e = E - 1;  // clamp; padded rows never written out
        ushort8 val;
        if (c < 16) {
            val = *(const ushort8*)&hb[(size_t)src[e] * HID + c * 8];
        } else if (c < 32) {
            val = *(const ushort8*)&hb[(size_t)dst[e] * HID + (c - 16) * 8];
        } else if (c == 32) {
            const float* p = &ce[pc[e] * 8];
#pragma unroll
            for (int j = 0; j < 8; ++j) val[j] = f2bf(p[j]);
        } else if (c == 33) {
            const float* p = &ce[rc[e] * 8];
#pragma unroll
            for (int j = 0; j < 8; ++j) val[j] = f2bf(p[j]);
        } else if (c == 34) {
            const float* p = &pe[pf[e] * 8];
#pragma unroll
            for (int j = 0; j < 8; ++j) val[j] = f2bf(p[j]);
        } else {
            const float* p = &num[(size_t)e * 5];
#pragma unroll
            for (int j = 0; j < 5; ++j) val[j] = f2bf(p[j]);
            val[5] = 0; val[6] = 0; val[7] = 0;
        }
        *(ushort8*)&y[t * LDW + c * 8] = val;
    }
    __syncthreads();

    int wave = tid >> 6;
    int lane = tid & 63;
    int l31 = lane & 31;
    int half = lane >> 5;
    int rowA = wave * 32 + l31;

    // ---- 3 hidden layers ----
    for (int layer = 0; layer < 3; ++layer) {
        const unsigned short* __restrict__ Wl = wp + (size_t)layer * 9 * 18 * 64 * 8;
        const float* __restrict__ bias = bh + layer * MLP_IN;

        // A fragments for this wave's 32 rows: 18 k-tiles of 16
        short8 afr[18];
#pragma unroll
        for (int kt = 0; kt < 18; ++kt)
            afr[kt] = *(const short8*)&y[rowA * LDW + kt * 16 + half * 8];
        __syncthreads();   // everyone captured A; y is now writable

        for (int ct = 0; ct < 9; ++ct) {
            f32x16 acc = {};
            const unsigned short* Wct = Wl + ((size_t)ct * 18 * 64 + lane) * 8;
            short8 bfr[18];
#pragma unroll
            for (int kt = 0; kt < 18; ++kt)
                bfr[kt] = *(const short8*)&Wct[kt * 64 * 8];  // coalesced: lane-contiguous
#pragma unroll
            for (int kt = 0; kt < 18; ++kt)
                acc = __builtin_amdgcn_mfma_f32_32x32x16_bf16(afr[kt], bfr[kt], acc, 0, 0, 0);

            int col = ct * 32 + l31;
            if (col < MLP_IN) {
                float bv = bias[col];
#pragma unroll
                for (int r = 0; r < 16; ++r) {
                    int rowm = (r & 3) + 8 * (r >> 2) + 4 * half;
                    float vv = fmaxf(acc[r] + bv, 0.f);
                    y[(wave * 32 + rowm) * LDW + col] = f2bf(vv);
                }
            }
        }
        __syncthreads();   // y fully updated for next layer
    }

    // ---- output layer: [285] @ Wo[285,2] + bo ----
    {
        int t = tid >> 1, oc = tid & 1;
        int e = e0 + t;
        if (e < E) {
            const unsigned short* yr = &y[t * LDW];
            float p0 = 0.f, p1 = 0.f, p2 = 0.f, p3 = 0.f;
            for (int kc = 0; kc < 35; ++kc) {   // cols 0..279 vectorized
                ushort8 yv = *(const ushort8*)&yr[kc * 8];
                int kb = kc * 8;
                p0 = fmaf(bf2f(yv[0]), Wo[(kb + 0) * 2 + oc], p0);
                p1 = fmaf(bf2f(yv[1]), Wo[(kb + 1) * 2 + oc], p1);
                p2 = fmaf(bf2f(yv[2]), Wo[(kb + 2) * 2 + oc], p2);
                p3 = fmaf(bf2f(yv[3]), Wo[(kb + 3) * 2 + oc], p3);
                p0 = fmaf(bf2f(yv[4]), Wo[(kb + 4) * 2 + oc], p0);
                p1 = fmaf(bf2f(yv[5]), Wo[(kb + 5) * 2 + oc], p1);
                p2 = fmaf(bf2f(yv[6]), Wo[(kb + 6) * 2 + oc], p2);
                p3 = fmaf(bf2f(yv[7]), Wo[(kb + 7) * 2 + oc], p3);
            }
            float acc = bo[oc] + (p0 + p1) + (p2 + p3);
            for (int k = 280; k < MLP_IN; ++k)
                acc = fmaf(bf2f(yr[k]), Wo[k * 2 + oc], acc);
            out[(size_t)e * 2 + oc] = acc;
        }
    }
}

extern "C" void kernel_launch(void* const* d_in, const int* in_sizes, int n_in,
                              void* d_out, int out_size, void* d_ws, size_t ws_size,
                              hipStream_t stream)
{
    const float* node_feats = (const float*)d_in[0];
    const float* numericals = (const float*)d_in[1];
    const float* W_emb = (const float*)d_in[2];
    const float* b_emb = (const float*)d_in[3];
    const float* WQ = (const float*)d_in[4];
    const float* bQ = (const float*)d_in[5];
    const float* WK = (const float*)d_in[6];
    const float* bK = (const float*)d_in[7];
    const float* WV = (const float*)d_in[8];
    const float* bV = (const float*)d_in[9];
    const float* WO = (const float*)d_in[10];
    const float* bO = (const float*)d_in[11];
    const float* ln1_g = (const float*)d_in[12];
    const float* ln1_b = (const float*)d_in[13];
    const float* ln2_g = (const float*)d_in[14];
    const float* ln2_b = (const float*)d_in[15];
    const float* W1 = (const float*)d_in[16];
    const float* b1 = (const float*)d_in[17];
    const float* W2 = (const float*)d_in[18];
    const float* b2 = (const float*)d_in[19];
    const float* curr_emb = (const float*)d_in[20];
    const float* pay_emb = (const float*)d_in[21];
    const float* mlp_Wh = (const float*)d_in[22];
    const float* mlp_bh = (const float*)d_in[23];
    const float* mlp_Wo = (const float*)d_in[24];
    const float* mlp_bo = (const float*)d_in[25];
    const int* src = (const int*)d_in[26];
    const int* dst = (const int*)d_in[27];
    const int* pc = (const int*)d_in[28];
    const int* rc = (const int*)d_in[29];
    const int* pf = (const int*)d_in[30];

    const int N = in_sizes[0] / 2;
    const int E = in_sizes[26];

    float* ws = (float*)d_ws;
    float* h   = ws;
    float* x   = h  + (size_t)N * HID;
    float* qb  = x  + (size_t)N * HID;
    float* kb  = qb + (size_t)N * HID;
    float* vb  = kb + (size_t)N * HID;
    float* at  = vb + (size_t)N * HID;
    unsigned short* hb = (unsigned short*)(at + (size_t)N * HID);
    unsigned short* wpk = hb + (size_t)N * HID;
    int* rowptr = (int*)(wpk + (size_t)3 * 9 * 18 * 64 * 8);
    int* deg    = rowptr + (N + 1);
    int* cursor = deg + N;
    int* ssrc   = cursor + N;

    // prep fragment-major bf16 MLP weights (graph-safe, reruns every call)
    prep_wp_kernel<<<(3 * 9 * 18 * 64 + 255) / 256, 256, 0, stream>>>(mlp_Wh, wpk);

    embed_kernel<<<(N * HID + 255) / 256, 256, 0, stream>>>(node_feats, W_emb, b_emb, h, N);

    // CSR build (once; src/dst constant across layers)
    hipMemsetAsync(deg, 0, (size_t)N * sizeof(int), stream);
    deg_kernel<<<(E + 255) / 256, 256, 0, stream>>>(dst, deg, E);
    scan_kernel<<<1, 256, 0, stream>>>(deg, rowptr, cursor, N);
    scatter_kernel<<<(E + 255) / 256, 256, 0, stream>>>(src, dst, cursor, ssrc, E);

    dim3 gg((N + 63) / 64, 2);
    int lnBlocks = (N + 3) / 4;

    for (int l = 0; l < NLAYERS; ++l) {
        ln_kernel<<<lnBlocks, 256, 0, stream>>>(h, x, ln1_g + l * HID, ln1_b + l * HID, N);
        gemm128_kernel<0><<<gg, 256, 0, stream>>>(x, WQ + (size_t)l * HID * HID, bQ + l * HID, nullptr, qb, N);
        gemm128_kernel<0><<<gg, 256, 0, stream>>>(x, WK + (size_t)l * HID * HID, bK + l * HID, nullptr, kb, N);
        gemm128_kernel<0><<<gg, 256, 0, stream>>>(x, WV + (size_t)l * HID * HID, bV + l * HID, nullptr, vb, N);

        attn_fused_kernel<<<(N + 3) / 4, 256, 0, stream>>>(qb, kb, vb, rowptr, ssrc, at, N);

        gemm128_kernel<2><<<gg, 256, 0, stream>>>(at, WO + (size_t)l * HID * HID, bO + l * HID, h, h, N);

        ln_kernel<<<lnBlocks, 256, 0, stream>>>(h, x, ln2_g + l * HID, ln2_b + l * HID, N);
        gemm128_kernel<1><<<gg, 256, 0, stream>>>(x, W1 + (size_t)l * HID * HID, b1 + l * HID, nullptr, qb, N);
        gemm128_kernel<2><<<gg, 256, 0, stream>>>(qb, W2 + (size_t)l * HID * HID, b2 + l * HID, h, h, N);
    }

    // bf16 copy of final h for the edge MLP gather
    prep_hb_kernel<<<(N * HID + 255) / 256, 256, 0, stream>>>(h, hb, N * HID);

    edge_mlp_mfma<<<(E + 127) / 128, 256, 0, stream>>>(
        hb, curr_emb, pay_emb, numericals, src, dst, pc, rc, pf,
        wpk, mlp_bh, mlp_Wo, mlp_bo, (float*)d_out, E);
}

// Round 5
// 1418.116 us; speedup vs baseline: 2.6633x; 1.2310x over previous
//
#include <hip/hip_runtime.h>

#define HID 128
#define NH 8
#define DH 16
#define NLAYERS 7
#define MLP_IN 285
#define MP 288          // padded MLP dim (18 x 16)
#define LDW 296         // LDS row stride in bf16 elems

typedef short short8 __attribute__((ext_vector_type(8)));
typedef float f32x4 __attribute__((ext_vector_type(4)));
typedef float f32x16 __attribute__((ext_vector_type(16)));
typedef unsigned short ushort8 __attribute__((ext_vector_type(8)));

__device__ inline unsigned short f2bf(float f) {
    union { float f; unsigned int u; } v; v.f = f;
    unsigned int r = v.u + 0x7FFF + ((v.u >> 16) & 1);
    return (unsigned short)(r >> 16);
}
__device__ inline float bf2f(unsigned short u) {
    union { unsigned int u; float f; } v; v.u = ((unsigned int)u) << 16;
    return v.f;
}

// ---------------- embed ----------------
__global__ __launch_bounds__(256) void embed_kernel(
    const float* __restrict__ nf, const float* __restrict__ We,
    const float* __restrict__ be, float* __restrict__ h, int N)
{
    int idx = blockIdx.x * 256 + threadIdx.x;
    if (idx >= N * HID) return;
    int n = idx >> 7, j = idx & 127;
    h[idx] = fmaf(nf[n * 2], We[j], fmaf(nf[n * 2 + 1], We[HID + j], be[j]));
}

// ---------------- fused LN1 + QKV: 32 rows/block ----------------
__global__ __launch_bounds__(256) void ln_qkv_kernel(
    const float* __restrict__ h,
    const float* __restrict__ g, const float* __restrict__ bb,
    const float* __restrict__ WQ, const float* __restrict__ bQ,
    const float* __restrict__ WK, const float* __restrict__ bK,
    const float* __restrict__ WV, const float* __restrict__ bV,
    float* __restrict__ qo, float* __restrict__ ko, float* __restrict__ vo, int M)
{
    __shared__ float Xs[32][132];
    int tid = threadIdx.x;
    int lane = tid & 63, wave = tid >> 6;
    int rowBase = blockIdx.x * 32;

    // LN of 8 rows per wave, h -> Xs
    for (int i = 0; i < 8; ++i) {
        int r = wave * 8 + i;
        int row = rowBase + r;
        float a0 = 0.f, a1 = 0.f;
        if (row < M) {
            a0 = h[(size_t)row * HID + lane];
            a1 = h[(size_t)row * HID + 64 + lane];
        }
        float s = a0 + a1;
#pragma unroll
        for (int off = 32; off > 0; off >>= 1) s += __shfl_down(s, off, 64);
        s = __shfl(s, 0, 64);
        float mu = s * (1.0f / 128.0f);
        float d0 = a0 - mu, d1 = a1 - mu;
        float v = d0 * d0 + d1 * d1;
#pragma unroll
        for (int off = 32; off > 0; off >>= 1) v += __shfl_down(v, off, 64);
        v = __shfl(v, 0, 64);
        float rr = rsqrtf(v * (1.0f / 128.0f) + 1e-5f);
        Xs[r][lane]      = d0 * rr * g[lane] + bb[lane];
        Xs[r][64 + lane] = d1 * rr * g[64 + lane] + bb[64 + lane];
    }
    __syncthreads();

    int cg = tid & 31;   // 32 col groups x 4 = 128 cols
    int rg = tid >> 5;   // 8 row groups x 4 rows = 32 rows

    const float* Ws[3] = {WQ, WK, WV};
    const float* bs[3] = {bQ, bK, bV};
    float* Os[3] = {qo, ko, vo};

    for (int m = 0; m < 3; ++m) {
        const float* __restrict__ W = Ws[m];
        float acc[4][4];
#pragma unroll
        for (int i = 0; i < 4; ++i)
#pragma unroll
            for (int j = 0; j < 4; ++j) acc[i][j] = 0.f;
        for (int k = 0; k < 128; k += 4) {
            float4 a[4];
#pragma unroll
            for (int i = 0; i < 4; ++i) a[i] = *(const float4*)&Xs[rg * 4 + i][k];
#pragma unroll
            for (int kk = 0; kk < 4; ++kk) {
                float4 w = *(const float4*)&W[(size_t)(k + kk) * HID + cg * 4];
#pragma unroll
                for (int i = 0; i < 4; ++i) {
                    float av = ((const float*)&a[i])[kk];
                    acc[i][0] = fmaf(av, w.x, acc[i][0]);
                    acc[i][1] = fmaf(av, w.y, acc[i][1]);
                    acc[i][2] = fmaf(av, w.z, acc[i][2]);
                    acc[i][3] = fmaf(av, w.w, acc[i][3]);
                }
            }
        }
        float4 bv = *(const float4*)&bs[m][cg * 4];
#pragma unroll
        for (int i = 0; i < 4; ++i) {
            int row = rowBase + rg * 4 + i;
            if (row < M) {
                float4 c;
                c.x = acc[i][0] + bv.x; c.y = acc[i][1] + bv.y;
                c.z = acc[i][2] + bv.z; c.w = acc[i][3] + bv.w;
                *(float4*)&Os[m][(size_t)row * HID + cg * 4] = c;
            }
        }
    }
}

// ---------------- fused WO+res -> LN2 -> W1+relu -> W2+res: 32 rows/block ----------------
__global__ __launch_bounds__(256) void post_kernel(
    const float* __restrict__ at, const float* __restrict__ hin,
    const float* __restrict__ WO, const float* __restrict__ bO,
    const float* __restrict__ g2, const float* __restrict__ b2g,
    const float* __restrict__ W1, const float* __restrict__ b1,
    const float* __restrict__ W2, const float* __restrict__ b2,
    float* __restrict__ hout, int M)
{
    __shared__ float As[32][132];   // at tile, later reused as LN output Xs
    __shared__ float Hs[32][132];   // h' = h + at@WO + bO
    __shared__ float Ts[32][132];   // relu(Xs@W1 + b1)
    int tid = threadIdx.x;
    int lane = tid & 63, wave = tid >> 6;
    int rowBase = blockIdx.x * 32;
    int cg = tid & 31;
    int rg = tid >> 5;

    // stage at, h
    for (int i = tid; i < 32 * 32; i += 256) {
        int r = i >> 5, c4 = i & 31;
        int row = rowBase + r;
        float4 va = make_float4(0.f, 0.f, 0.f, 0.f), vh = va;
        if (row < M) {
            va = *(const float4*)&at[(size_t)row * HID + c4 * 4];
            vh = *(const float4*)&hin[(size_t)row * HID + c4 * 4];
        }
        *(float4*)&As[r][c4 * 4] = va;
        *(float4*)&Hs[r][c4 * 4] = vh;
    }
    __syncthreads();

    // GEMM1: Hs += As @ WO + bO
    {
        float acc[4][4];
#pragma unroll
        for (int i = 0; i < 4; ++i)
#pragma unroll
            for (int j = 0; j < 4; ++j) acc[i][j] = 0.f;
        for (int k = 0; k < 128; k += 4) {
            float4 a[4];
#pragma unroll
            for (int i = 0; i < 4; ++i) a[i] = *(const float4*)&As[rg * 4 + i][k];
#pragma unroll
            for (int kk = 0; kk < 4; ++kk) {
                float4 w = *(const float4*)&WO[(size_t)(k + kk) * HID + cg * 4];
#pragma unroll
                for (int i = 0; i < 4; ++i) {
                    float av = ((const float*)&a[i])[kk];
                    acc[i][0] = fmaf(av, w.x, acc[i][0]);
                    acc[i][1] = fmaf(av, w.y, acc[i][1]);
                    acc[i][2] = fmaf(av, w.z, acc[i][2]);
                    acc[i][3] = fmaf(av, w.w, acc[i][3]);
                }
            }
        }
        float4 bv = *(const float4*)&bO[cg * 4];
#pragma unroll
        for (int i = 0; i < 4; ++i) {
            float* hp = &Hs[rg * 4 + i][cg * 4];
            hp[0] += acc[i][0] + bv.x;
            hp[1] += acc[i][1] + bv.y;
            hp[2] += acc[i][2] + bv.z;
            hp[3] += acc[i][3] + bv.w;
        }
    }
    __syncthreads();

    // LN2: Hs -> As (reused as Xs)
    for (int i = 0; i < 8; ++i) {
        int r = wave * 8 + i;
        float a0 = Hs[r][lane];
        float a1 = Hs[r][64 + lane];
        float s = a0 + a1;
#pragma unroll
        for (int off = 32; off > 0; off >>= 1) s += __shfl_down(s, off, 64);
        s = __shfl(s, 0, 64);
        float mu = s * (1.0f / 128.0f);
        float d0 = a0 - mu, d1 = a1 - mu;
        float v = d0 * d0 + d1 * d1;
#pragma unroll
        for (int off = 32; off > 0; off >>= 1) v += __shfl_down(v, off, 64);
        v = __shfl(v, 0, 64);
        float rr = rsqrtf(v * (1.0f / 128.0f) + 1e-5f);
        As[r][lane]      = d0 * rr * g2[lane] + b2g[lane];
        As[r][64 + lane] = d1 * rr * g2[64 + lane] + b2g[64 + lane];
    }
    __syncthreads();

    // GEMM2: Ts = relu(As @ W1 + b1)
    {
        float acc[4][4];
#pragma unroll
        for (int i = 0; i < 4; ++i)
#pragma unroll
            for (int j = 0; j < 4; ++j) acc[i][j] = 0.f;
        for (int k = 0; k < 128; k += 4) {
            float4 a[4];
#pragma unroll
            for (int i = 0; i < 4; ++i) a[i] = *(const float4*)&As[rg * 4 + i][k];
#pragma unroll
            for (int kk = 0; kk < 4; ++kk) {
                float4 w = *(const float4*)&W1[(size_t)(k + kk) * HID + cg * 4];
#pragma unroll
                for (int i = 0; i < 4; ++i) {
                    float av = ((const float*)&a[i])[kk];
                    acc[i][0] = fmaf(av, w.x, acc[i][0]);
                    acc[i][1] = fmaf(av, w.y, acc[i][1]);
                    acc[i][2] = fmaf(av, w.z, acc[i][2]);
                    acc[i][3] = fmaf(av, w.w, acc[i][3]);
                }
            }
        }
        float4 bv = *(const float4*)&b1[cg * 4];
#pragma unroll
        for (int i = 0; i < 4; ++i) {
            float* tp = &Ts[rg * 4 + i][cg * 4];
            tp[0] = fmaxf(acc[i][0] + bv.x, 0.f);
            tp[1] = fmaxf(acc[i][1] + bv.y, 0.f);
            tp[2] = fmaxf(acc[i][2] + bv.z, 0.f);
            tp[3] = fmaxf(acc[i][3] + bv.w, 0.f);
        }
    }
    __syncthreads();

    // GEMM3: hout = Hs + Ts @ W2 + b2
    {
        float acc[4][4];
#pragma unroll
        for (int i = 0; i < 4; ++i)
#pragma unroll
            for (int j = 0; j < 4; ++j) acc[i][j] = 0.f;
        for (int k = 0; k < 128; k += 4) {
            float4 a[4];
#pragma unroll
            for (int i = 0; i < 4; ++i) a[i] = *(const float4*)&Ts[rg * 4 + i][k];
#pragma unroll
            for (int kk = 0; kk < 4; ++kk) {
                float4 w = *(const float4*)&W2[(size_t)(k + kk) * HID + cg * 4];
#pragma unroll
                for (int i = 0; i < 4; ++i) {
                    float av = ((const float*)&a[i])[kk];
                    acc[i][0] = fmaf(av, w.x, acc[i][0]);
                    acc[i][1] = fmaf(av, w.y, acc[i][1]);
                    acc[i][2] = fmaf(av, w.z, acc[i][2]);
                    acc[i][3] = fmaf(av, w.w, acc[i][3]);
                }
            }
        }
        float4 bv = *(const float4*)&b2[cg * 4];
#pragma unroll
        for (int i = 0; i < 4; ++i) {
            int row = rowBase + rg * 4 + i;
            if (row < M) {
                float* hp = &Hs[rg * 4 + i][cg * 4];
                float4 c;
                c.x = hp[0] + acc[i][0] + bv.x;
                c.y = hp[1] + acc[i][1] + bv.y;
                c.z = hp[2] + acc[i][2] + bv.z;
                c.w = hp[3] + acc[i][3] + bv.w;
                *(float4*)&hout[(size_t)row * HID + cg * 4] = c;
            }
        }
    }
}

// ---------------- CSR build ----------------
__global__ __launch_bounds__(256) void deg_kernel(
    const int* __restrict__ dst, int* __restrict__ deg, int E)
{
    int e = blockIdx.x * 256 + threadIdx.x;
    if (e < E) atomicAdd(&deg[dst[e]], 1);
}

__global__ __launch_bounds__(256) void scan_kernel(
    const int* __restrict__ deg, int* __restrict__ rowptr,
    int* __restrict__ cursor, int N)
{
    __shared__ int sums[256];
    int tid = threadIdx.x;
    int chunk = (N + 255) / 256;
    int lo = tid * chunk;
    int hi = lo + chunk; if (hi > N) hi = N;
    int s = 0;
    for (int i = lo; i < hi && i >= 0; ++i) s += deg[i];
    sums[tid] = s;
    __syncthreads();
    for (int off = 1; off < 256; off <<= 1) {
        int v = (tid >= off) ? sums[tid - off] : 0;
        __syncthreads();
        sums[tid] += v;
        __syncthreads();
    }
    int base = (tid == 0) ? 0 : sums[tid - 1];
    for (int i = lo; i < hi; ++i) {
        rowptr[i] = base; cursor[i] = base; base += deg[i];
    }
    if (tid == 255) rowptr[N] = sums[255];
}

__global__ __launch_bounds__(256) void scatter_kernel(
    const int* __restrict__ src, const int* __restrict__ dst,
    int* __restrict__ cursor, int* __restrict__ ssrc, int E)
{
    int e = blockIdx.x * 256 + threadIdx.x;
    if (e < E) {
        int p = atomicAdd(&cursor[dst[e]], 1);
        ssrc[p] = src[e];
    }
}

// ---------------- fused segment-softmax attention ----------------
__global__ __launch_bounds__(256) void attn_fused_kernel(
    const float* __restrict__ q, const float* __restrict__ k,
    const float* __restrict__ v, const int* __restrict__ rowptr,
    const int* __restrict__ ssrc, float* __restrict__ at, int N)
{
    int node = blockIdx.x * 4 + (threadIdx.x >> 6);
    int lane = threadIdx.x & 63;
    if (node >= N) return;
    int beg = rowptr[node], end = rowptr[node + 1];
    float q0 = q[(size_t)node * HID + lane];
    float q1 = q[(size_t)node * HID + 64 + lane];
    float acc0 = 0.f, acc1 = 0.f, den0 = 0.f, den1 = 0.f;
    for (int i = beg; i < end; ++i) {
        int s = ssrc[i];
        float k0 = k[(size_t)s * HID + lane];
        float k1 = k[(size_t)s * HID + 64 + lane];
        float p0 = q0 * k0, p1 = q1 * k1;
#pragma unroll
        for (int off = 1; off < 16; off <<= 1) {
            p0 += __shfl_xor(p0, off, 64);
            p1 += __shfl_xor(p1, off, 64);
        }
        float w0 = __expf(p0 * 0.25f);
        float w1 = __expf(p1 * 0.25f);
        den0 += w0; den1 += w1;
        acc0 = fmaf(w0, v[(size_t)s * HID + lane], acc0);
        acc1 = fmaf(w1, v[(size_t)s * HID + 64 + lane], acc1);
    }
    at[(size_t)node * HID + lane]      = (den0 > 0.f) ? acc0 / den0 : 0.f;
    at[(size_t)node * HID + 64 + lane] = (den1 > 0.f) ? acc1 / den1 : 0.f;
}

// ---------------- prep: fragment-major packed bf16 MLP hidden weights ----------------
__global__ __launch_bounds__(256) void prep_wp_kernel(
    const float* __restrict__ Wh, unsigned short* __restrict__ wp)
{
    int idx = blockIdx.x * 256 + threadIdx.x;
    if (idx >= 3 * 9 * 18 * 64) return;
    int lane = idx & 63;
    int r = idx >> 6;
    int kt = r % 18; r /= 18;
    int ct = r % 9;
    int layer = r / 9;
    int n = ct * 32 + (lane & 31);
    int kbase = kt * 16 + (lane >> 5) * 8;
    ushort8 val;
#pragma unroll
    for (int j = 0; j < 8; ++j) {
        int k = kbase + j;
        float v = (n < MLP_IN && k < MLP_IN)
            ? Wh[(size_t)layer * MLP_IN * MLP_IN + (size_t)k * MLP_IN + n] : 0.f;
        val[j] = f2bf(v);
    }
    *(ushort8*)&wp[(size_t)idx * 8] = val;
}

__global__ __launch_bounds__(256) void prep_hb_kernel(
    const float* __restrict__ h, unsigned short* __restrict__ hb, int n)
{
    int idx = blockIdx.x * 256 + threadIdx.x;
    if (idx >= n) return;
    hb[idx] = f2bf(h[idx]);
}

// ---------------- fused edge classifier MLP: 32x32x16 MFMA, batched B loads ----------------
__global__ __launch_bounds__(256, 2) void edge_mlp_mfma(
    const unsigned short* __restrict__ hb, const float* __restrict__ ce,
    const float* __restrict__ pe, const float* __restrict__ num,
    const int* __restrict__ src, const int* __restrict__ dst,
    const int* __restrict__ pc, const int* __restrict__ rc,
    const int* __restrict__ pf,
    const unsigned short* __restrict__ wp, const float* __restrict__ bh,
    const float* __restrict__ Wo, const float* __restrict__ bo,
    float* __restrict__ out, int E)
{
    __shared__ unsigned short y[128 * LDW];
    int tid = threadIdx.x;
    int e0 = blockIdx.x * 128;

    for (int i = tid; i < 128 * 36; i += 256) {
        int t = i / 36;
        int c = i - t * 36;
        int e = e0 + t;
        if (e >= E) e = E - 1;
        ushort8 val;
        if (c < 16) {
            val = *(const ushort8*)&hb[(size_t)src[e] * HID + c * 8];
        } else if (c < 32) {
            val = *(const ushort8*)&hb[(size_t)dst[e] * HID + (c - 16) * 8];
        } else if (c == 32) {
            const float* p = &ce[pc[e] * 8];
#pragma unroll
            for (int j = 0; j < 8; ++j) val[j] = f2bf(p[j]);
        } else if (c == 33) {
            const float* p = &ce[rc[e] * 8];
#pragma unroll
            for (int j = 0; j < 8; ++j) val[j] = f2bf(p[j]);
        } else if (c == 34) {
            const float* p = &pe[pf[e] * 8];
#pragma unroll
            for (int j = 0; j < 8; ++j) val[j] = f2bf(p[j]);
        } else {
            const float* p = &num[(size_t)e * 5];
#pragma unroll
            for (int j = 0; j < 5; ++j) val[j] = f2bf(p[j]);
            val[5] = 0; val[6] = 0; val[7] = 0;
        }
        *(ushort8*)&y[t * LDW + c * 8] = val;
    }
    __syncthreads();

    int wave = tid >> 6;
    int lane = tid & 63;
    int l31 = lane & 31;
    int half = lane >> 5;
    int rowA = wave * 32 + l31;

    for (int layer = 0; layer < 3; ++layer) {
        const unsigned short* __restrict__ Wl = wp + (size_t)layer * 9 * 18 * 64 * 8;
        const float* __restrict__ bias = bh + layer * MLP_IN;

        short8 afr[18];
#pragma unroll
        for (int kt = 0; kt < 18; ++kt)
            afr[kt] = *(const short8*)&y[rowA * LDW + kt * 16 + half * 8];
        __syncthreads();

        for (int ct = 0; ct < 9; ++ct) {
            const unsigned short* Wct = Wl + ((size_t)ct * 18 * 64 + lane) * 8;
            short8 bfr[18];
#pragma unroll
            for (int kt = 0; kt < 18; ++kt)
                bfr[kt] = *(const short8*)&Wct[kt * 512];
            // force all 18 B loads to issue before the MFMA chain (batched vmcnt drain);
            // loads of ct+1 may still hoist into this region from the next one.
            __builtin_amdgcn_sched_barrier(0);
            f32x16 accA = {}, accB = {};
#pragma unroll
            for (int kt = 0; kt < 18; kt += 2) {
                accA = __builtin_amdgcn_mfma_f32_32x32x16_bf16(afr[kt],     bfr[kt],     accA, 0, 0, 0);
                accB = __builtin_amdgcn_mfma_f32_32x32x16_bf16(afr[kt + 1], bfr[kt + 1], accB, 0, 0, 0);
            }
            int col = ct * 32 + l31;
            if (col < MLP_IN) {
                float bv = bias[col];
#pragma unroll
                for (int r = 0; r < 16; ++r) {
                    int rowm = (r & 3) + 8 * (r >> 2) + 4 * half;
                    float vv = fmaxf(accA[r] + accB[r] + bv, 0.f);
                    y[(wave * 32 + rowm) * LDW + col] = f2bf(vv);
                }
            }
        }
        __syncthreads();
    }

    // output layer
    {
        int t = tid >> 1, oc = tid & 1;
        int e = e0 + t;
        if (e < E) {
            const unsigned short* yr = &y[t * LDW];
            float p0 = 0.f, p1 = 0.f, p2 = 0.f, p3 = 0.f;
            for (int kc = 0; kc < 35; ++kc) {
                ushort8 yv = *(const ushort8*)&yr[kc * 8];
                int kb = kc * 8;
                p0 = fmaf(bf2f(yv[0]), Wo[(kb + 0) * 2 + oc], p0);
                p1 = fmaf(bf2f(yv[1]), Wo[(kb + 1) * 2 + oc], p1);
                p2 = fmaf(bf2f(yv[2]), Wo[(kb + 2) * 2 + oc], p2);
                p3 = fmaf(bf2f(yv[3]), Wo[(kb + 3) * 2 + oc], p3);
                p0 = fmaf(bf2f(yv[4]), Wo[(kb + 4) * 2 + oc], p0);
                p1 = fmaf(bf2f(yv[5]), Wo[(kb + 5) * 2 + oc], p1);
                p2 = fmaf(bf2f(yv[6]), Wo[(kb + 6) * 2 + oc], p2);
                p3 = fmaf(bf2f(yv[7]), Wo[(kb + 7) * 2 + oc], p3);
            }
            float acc = bo[oc] + (p0 + p1) + (p2 + p3);
            for (int k = 280; k < MLP_IN; ++k)
                acc = fmaf(bf2f(yr[k]), Wo[k * 2 + oc], acc);
            out[(size_t)e * 2 + oc] = acc;
        }
    }
}

extern "C" void kernel_launch(void* const* d_in, const int* in_sizes, int n_in,
                              void* d_out, int out_size, void* d_ws, size_t ws_size,
                              hipStream_t stream)
{
    const float* node_feats = (const float*)d_in[0];
    const float* numericals = (const float*)d_in[1];
    const float* W_emb = (const float*)d_in[2];
    const float* b_emb = (const float*)d_in[3];
    const float* WQ = (const float*)d_in[4];
    const float* bQ = (const float*)d_in[5];
    const float* WK = (const float*)d_in[6];
    const float* bK = (const float*)d_in[7];
    const float* WV = (const float*)d_in[8];
    const float* bV = (const float*)d_in[9];
    const float* WO = (const float*)d_in[10];
    const float* bO = (const float*)d_in[11];
    const float* ln1_g = (const float*)d_in[12];
    const float* ln1_b = (const float*)d_in[13];
    const float* ln2_g = (const float*)d_in[14];
    const float* ln2_b = (const float*)d_in[15];
    const float* W1 = (const float*)d_in[16];
    const float* b1 = (const float*)d_in[17];
    const float* W2 = (const float*)d_in[18];
    const float* b2 = (const float*)d_in[19];
    const float* curr_emb = (const float*)d_in[20];
    const float* pay_emb = (const float*)d_in[21];
    const float* mlp_Wh = (const float*)d_in[22];
    const float* mlp_bh = (const float*)d_in[23];
    const float* mlp_Wo = (const float*)d_in[24];
    const float* mlp_bo = (const float*)d_in[25];
    const int* src = (const int*)d_in[26];
    const int* dst = (const int*)d_in[27];
    const int* pc = (const int*)d_in[28];
    const int* rc = (const int*)d_in[29];
    const int* pf = (const int*)d_in[30];

    const int N = in_sizes[0] / 2;
    const int E = in_sizes[26];

    float* ws = (float*)d_ws;
    float* h   = ws;
    float* x   = h  + (size_t)N * HID;   // unused slot kept for layout stability
    float* qb  = x  + (size_t)N * HID;
    float* kb  = qb + (size_t)N * HID;
    float* vb  = kb + (size_t)N * HID;
    float* at  = vb + (size_t)N * HID;
    unsigned short* hb = (unsigned short*)(at + (size_t)N * HID);
    unsigned short* wpk = hb + (size_t)N * HID;
    int* rowptr = (int*)(wpk + (size_t)3 * 9 * 18 * 64 * 8);
    int* deg    = rowptr + (N + 1);
    int* cursor = deg + N;
    int* ssrc   = cursor + N;

    prep_wp_kernel<<<(3 * 9 * 18 * 64 + 255) / 256, 256, 0, stream>>>(mlp_Wh, wpk);

    embed_kernel<<<(N * HID + 255) / 256, 256, 0, stream>>>(node_feats, W_emb, b_emb, h, N);

    hipMemsetAsync(deg, 0, (size_t)N * sizeof(int), stream);
    deg_kernel<<<(E + 255) / 256, 256, 0, stream>>>(dst, deg, E);
    scan_kernel<<<1, 256, 0, stream>>>(deg, rowptr, cursor, N);
    scatter_kernel<<<(E + 255) / 256, 256, 0, stream>>>(src, dst, cursor, ssrc, E);

    int nodeBlocks = (N + 31) / 32;

    for (int l = 0; l < NLAYERS; ++l) {
        ln_qkv_kernel<<<nodeBlocks, 256, 0, stream>>>(
            h, ln1_g + l * HID, ln1_b + l * HID,
            WQ + (size_t)l * HID * HID, bQ + l * HID,
            WK + (size_t)l * HID * HID, bK + l * HID,
            WV + (size_t)l * HID * HID, bV + l * HID,
            qb, kb, vb, N);

        attn_fused_kernel<<<(N + 3) / 4, 256, 0, stream>>>(qb, kb, vb, rowptr, ssrc, at, N);

        post_kernel<<<nodeBlocks, 256, 0, stream>>>(
            at, h,
            WO + (size_t)l * HID * HID, bO + l * HID,
            ln2_g + l * HID, ln2_b + l * HID,
            W1 + (size_t)l * HID * HID, b1 + l * HID,
            W2 + (size_t)l * HID * HID, b2 + l * HID,
            h, N);
    }

    prep_hb_kernel<<<(N * HID + 255) / 256, 256, 0, stream>>>(h, hb, N * HID);

    edge_mlp_mfma<<<(E + 127) / 128, 256, 0, stream>>>(
        hb, curr_emb, pay_emb, numericals, src, dst, pc, rc, pf,
        wpk, mlp_bh, mlp_Wo, mlp_bo, (float*)d_out, E);
}